// Round 10
// baseline (173.074 us; speedup 1.0000x reference)
//
#include <hip/hip_runtime.h>
#include <stdint.h>

typedef unsigned short u16;
typedef __attribute__((ext_vector_type(8))) short short8;
typedef __attribute__((ext_vector_type(4))) float f32x4;
typedef __attribute__((ext_vector_type(4))) unsigned short u16x4;

#define DEVI __device__ __forceinline__

DEVI u16 f2bf(float f) {
  uint32_t u = __builtin_bit_cast(uint32_t, f);
  u += 0x7fffu + ((u >> 16) & 1u);
  return (u16)(u >> 16);
}

DEVI float bf2f(u16 u) {
  uint32_t v = ((uint32_t)u) << 16;
  return __builtin_bit_cast(float, v);
}

DEVI void gload_lds16(const void* g, void* l) {
  __builtin_amdgcn_global_load_lds(
      (const __attribute__((address_space(1))) void*)g,
      (__attribute__((address_space(3))) void*)(uint32_t)(uintptr_t)l,
      16, 0, 0);
}

// ---------------- convert / concat fp32 -> bf16 ----------------
__global__ void cvt_cat_bf16(const float* __restrict__ a, const float* __restrict__ b,
                             u16* __restrict__ dst, long total) {
  for (long i = ((long)blockIdx.x * 256 + threadIdx.x) * 4; i < total;
       i += (long)gridDim.x * 1024) {
    const long row = i >> 11;
    const long c = i & 2047;
    const float* src = (c < 1024) ? (a + row * 1024 + c) : (b + row * 1024 + (c - 1024));
    const float4 v = *(const float4*)src;
    u16x4 o = {f2bf(v.x), f2bf(v.y), f2bf(v.z), f2bf(v.w)};
    *(u16x4*)(dst + i) = o;
  }
}

__global__ void cvt_bf16(const float* __restrict__ a, u16* __restrict__ dst, long total) {
  for (long i = ((long)blockIdx.x * 256 + threadIdx.x) * 4; i < total;
       i += (long)gridDim.x * 1024) {
    const float4 v = *(const float4*)(a + i);
    u16x4 o = {f2bf(v.x), f2bf(v.y), f2bf(v.z), f2bf(v.w)};
    *(u16x4*)(dst + i) = o;
  }
}

// ---------------- bf16 GEMM 128^2 (m97 structure), fp32 out — proj ------------
__global__ __launch_bounds__(256, 2)
void gemm_bt(const u16* __restrict__ A, const u16* __restrict__ B,
             float* __restrict__ C, const float* __restrict__ bias1,
             const float* __restrict__ bias2, int M, int N, int K) {
  __shared__ u16 As[128 * 32];
  __shared__ u16 Bs[128 * 32];
  const int t = threadIdx.x;
  const int w = t >> 6, l = t & 63;
  const int l15 = l & 15, lg = l >> 4;
  const int bm = blockIdx.x, bn = blockIdx.y;
  const int wr = (w >> 1) * 64, wc = (w & 1) * 64;
  f32x4 acc[4][4] = {};
  const int c0 = w * 64 + l;

  for (int kt = 0; kt < (K >> 5); ++kt) {
#pragma unroll
    for (int i = 0; i < 2; ++i) {
      const int c = i * 256 + c0;
      const int row = c >> 2, seg = c & 3;
      gload_lds16(A + (long)(bm * 128 + row) * K + kt * 32 + seg * 8,
                  (char*)As + w * 1024 + i * 4096);
      gload_lds16(B + (long)(bn * 128 + row) * K + kt * 32 + seg * 8,
                  (char*)Bs + w * 1024 + i * 4096);
    }
    __syncthreads();
    short8 af[4], bfr[4];
#pragma unroll
    for (int m = 0; m < 4; ++m)
      af[m] = *(const short8*)&As[(wr + m * 16 + l15) * 32 + lg * 8];
#pragma unroll
    for (int n = 0; n < 4; ++n)
      bfr[n] = *(const short8*)&Bs[(wc + n * 16 + l15) * 32 + lg * 8];
#pragma unroll
    for (int m = 0; m < 4; ++m)
#pragma unroll
      for (int n = 0; n < 4; ++n)
        acc[m][n] = __builtin_amdgcn_mfma_f32_16x16x32_bf16(af[m], bfr[n], acc[m][n], 0, 0, 0);
    __syncthreads();
  }
#pragma unroll
  for (int m = 0; m < 4; ++m) {
    const int row0 = bm * 128 + wr + m * 16 + lg * 4;
#pragma unroll
    for (int n = 0; n < 4; ++n) {
      const int col = bn * 128 + wc + n * 16 + l15;
      float bia = 0.f;
      if (bias1) bia += bias1[col];
      if (bias2) bia += bias2[col];
#pragma unroll
      for (int r = 0; r < 4; ++r)
        C[(long)(row0 + r) * N + col] = acc[m][n][r] + bia;
    }
  }
}

// ---------------- same structure, bf16 out — QKV+dt fused GEMM ----------------
__global__ __launch_bounds__(256, 2)
void gemm_bt_b16(const u16* __restrict__ A, const u16* __restrict__ B,
                 u16* __restrict__ C, const float* __restrict__ bias1,
                 const float* __restrict__ bias2, int M, int N, int K) {
  __shared__ u16 As[128 * 32];
  __shared__ u16 Bs[128 * 32];
  const int t = threadIdx.x;
  const int w = t >> 6, l = t & 63;
  const int l15 = l & 15, lg = l >> 4;
  const int bm = blockIdx.x, bn = blockIdx.y;
  const int wr = (w >> 1) * 64, wc = (w & 1) * 64;
  f32x4 acc[4][4] = {};
  const int c0 = w * 64 + l;

  for (int kt = 0; kt < (K >> 5); ++kt) {
#pragma unroll
    for (int i = 0; i < 2; ++i) {
      const int c = i * 256 + c0;
      const int row = c >> 2, seg = c & 3;
      gload_lds16(A + (long)(bm * 128 + row) * K + kt * 32 + seg * 8,
                  (char*)As + w * 1024 + i * 4096);
      gload_lds16(B + (long)(bn * 128 + row) * K + kt * 32 + seg * 8,
                  (char*)Bs + w * 1024 + i * 4096);
    }
    __syncthreads();
    short8 af[4], bfr[4];
#pragma unroll
    for (int m = 0; m < 4; ++m)
      af[m] = *(const short8*)&As[(wr + m * 16 + l15) * 32 + lg * 8];
#pragma unroll
    for (int n = 0; n < 4; ++n)
      bfr[n] = *(const short8*)&Bs[(wc + n * 16 + l15) * 32 + lg * 8];
#pragma unroll
    for (int m = 0; m < 4; ++m)
#pragma unroll
      for (int n = 0; n < 4; ++n)
        acc[m][n] = __builtin_amdgcn_mfma_f32_16x16x32_bf16(af[m], bfr[n], acc[m][n], 0, 0, 0);
    __syncthreads();
  }
#pragma unroll
  for (int m = 0; m < 4; ++m) {
    const int row0 = bm * 128 + wr + m * 16 + lg * 4;
#pragma unroll
    for (int n = 0; n < 4; ++n) {
      const int col = bn * 128 + wc + n * 16 + l15;
      float bia = 0.f;
      if (bias1) bia += bias1[col];
      if (bias2) bia += bias2[col];
#pragma unroll
      for (int r = 0; r < 4; ++r)
        C[(long)(row0 + r) * N + col] = f2bf(acc[m][n][r] + bia);
    }
  }
}

// ---------------- fuse: split qkv (bf16), vres mix, LN(q,k), RoPE ----------------
__global__ __launch_bounds__(256)
void fuse_qkv2(const u16* __restrict__ qkv, const float* __restrict__ vres,
               const float* __restrict__ rope,
               const float* __restrict__ qg, const float* __restrict__ qb,
               const float* __restrict__ kg, const float* __restrict__ kb,
               const float* __restrict__ pl1, const float* __restrict__ pl2,
               u16* __restrict__ Q, u16* __restrict__ Ksw, u16* __restrict__ VTsw) {
  __shared__ u16 Vl[64][72];
  const int t = threadIdx.x, w = t >> 6, d = t & 63;
  const int bh = blockIdx.x, ntile = blockIdx.y;
  const int b = bh >> 4, h = bh & 15, n0 = ntile * 64;
  const float l1 = pl1[0], l2 = pl2[0];
  const float gq = qg[d], bq = qb[d];
  const float gk = kg[d], bk = kb[d];
  const float sgn = (d < 32) ? -1.f : 1.f;
  const int c = d >> 3, d7 = d & 7;

  for (int i = 0; i < 16; ++i) {
    const int nl = w * 16 + i;
    const int n = n0 + nl;
    const long base = ((long)(b * 1024 + n)) * 3072 + h * 64 + d;
    float q = bf2f(qkv[base]);
    float k = bf2f(qkv[base + 1024]);
    float v = bf2f(qkv[base + 2048]);
    v = l1 * v + l2 * vres[((long)(bh * 1024 + n)) * 64 + d];
    const float sinv = rope[n * 128 + d];
    const float cosv = rope[n * 128 + 64 + d];
    float s = q;
#pragma unroll
    for (int off = 1; off < 64; off <<= 1) s += __shfl_xor(s, off);
    const float qc = q - s * (1.f / 64.f);
    float vs = qc * qc;
#pragma unroll
    for (int off = 1; off < 64; off <<= 1) vs += __shfl_xor(vs, off);
    const float qn = qc * (1.f / sqrtf(vs * (1.f / 64.f) + 1e-5f)) * gq + bq;
    float s2 = k;
#pragma unroll
    for (int off = 1; off < 64; off <<= 1) s2 += __shfl_xor(s2, off);
    const float kc = k - s2 * (1.f / 64.f);
    float vs2 = kc * kc;
#pragma unroll
    for (int off = 1; off < 64; off <<= 1) vs2 += __shfl_xor(vs2, off);
    const float kn = kc * (1.f / sqrtf(vs2 * (1.f / 64.f) + 1e-5f)) * gk + bk;
    const float qo = __shfl_xor(qn, 32);
    const float ko = __shfl_xor(kn, 32);
    const float qr = qn * cosv + sgn * qo * sinv;
    const float kr = kn * cosv + sgn * ko * sinv;
    Q[(long)bh * 65536 + (long)n * 64 + d] = f2bf(qr);
    Ksw[(long)bh * 65536 + (long)n * 64 + ((c ^ (n & 7)) * 8 + d7)] = f2bf(kr);
    Vl[nl][d] = f2bf(v);
  }
  __syncthreads();
#pragma unroll
  for (int i = 0; i < 2; ++i) {
    const int task = i * 256 + t;
    const int dd = task >> 3, cc = task & 7;
    short8 o;
#pragma unroll
    for (int u = 0; u < 8; ++u) o[u] = (short)Vl[cc * 8 + u][dd];
    *(short8*)&VTsw[((long)(bh * 64 + dd)) * 1024 + n0 + ((cc ^ (dd & 7)) * 8)] = o;
  }
}

// ---------------- flash attention fwd: swapped QK^T and PV (proven r1-r5) -----
__global__ __launch_bounds__(256, 4)
void attn_fwd2(const u16* __restrict__ Q, const u16* __restrict__ Ksw,
               const u16* __restrict__ VTsw, u16* __restrict__ Out) {
  __shared__ u16 Kl[64 * 64];
  __shared__ u16 Vl[64 * 64];
  __shared__ u16 Pl[4][16 * 64];
  const int t = threadIdx.x, w = t >> 6, l = t & 63;
  const int l15 = l & 15, lg = l >> 4;
  const int x7 = l15 & 7;
  const int bh = blockIdx.x, q0 = blockIdx.y * 64;
  const long bo = (long)bh * 65536;
  u16* Plw = &Pl[w][0];

  const int qrow = q0 + w * 16 + l15;
  short8 qf[2];
#pragma unroll
  for (int ks = 0; ks < 2; ++ks)
    qf[ks] = *(const short8*)&Q[bo + (long)qrow * 64 + ks * 32 + lg * 8];

  f32x4 acc[4] = {};
  float m_run = -1e30f, l_run = 0.f;

  for (int kv = 0; kv < 16; ++kv) {
    const int kvb = kv * 64;
#pragma unroll
    for (int i = 0; i < 2; ++i) {
      const int idx = i * 256 + t;
      const int row = idx >> 3, seg = idx & 7;
      gload_lds16(Ksw + bo + (long)(kvb + row) * 64 + seg * 8, (char*)Kl + idx * 16);
      gload_lds16(VTsw + bo + (long)row * 1024 + kvb + seg * 8, (char*)Vl + idx * 16);
    }
    __syncthreads();
    f32x4 p[4];
#pragma unroll
    for (int mt = 0; mt < 4; ++mt) {
      f32x4 ps = {};
#pragma unroll
      for (int ks = 0; ks < 2; ++ks) {
        const short8 kf =
            *(const short8*)&Kl[(mt * 16 + l15) * 64 + (((ks * 4 + lg) ^ x7) * 8)];
        ps = __builtin_amdgcn_mfma_f32_16x16x32_bf16(kf, qf[ks], ps, 0, 0, 0);
      }
      p[mt] = ps;
    }
    float mx = p[0][0];
#pragma unroll
    for (int mt = 0; mt < 4; ++mt)
#pragma unroll
      for (int r = 0; r < 4; ++r) mx = fmaxf(mx, p[mt][r]);
    mx = fmaxf(mx, __shfl_xor(mx, 16));
    mx = fmaxf(mx, __shfl_xor(mx, 32));
    const float mnew = fmaxf(m_run, mx * 0.125f);
    const float alpha = __expf(m_run - mnew);
    m_run = mnew;
    float sum = 0.f;
#pragma unroll
    for (int mt = 0; mt < 4; ++mt)
#pragma unroll
      for (int r = 0; r < 4; ++r) {
        const float e = __expf(p[mt][r] * 0.125f - mnew);
        p[mt][r] = e;
        sum += e;
      }
    sum += __shfl_xor(sum, 16);
    sum += __shfl_xor(sum, 32);
    l_run = l_run * alpha + sum;
#pragma unroll
    for (int mt = 0; mt < 4; ++mt) {
      const int c = mt * 2 + (lg >> 1);
      char* bp = (char*)Plw + l15 * 128 + ((c ^ x7) * 16) + (lg & 1) * 8;
      *(uint32_t*)bp = (uint32_t)f2bf(p[mt][0]) | ((uint32_t)f2bf(p[mt][1]) << 16);
      *(uint32_t*)(bp + 4) = (uint32_t)f2bf(p[mt][2]) | ((uint32_t)f2bf(p[mt][3]) << 16);
    }
#pragma unroll
    for (int mt = 0; mt < 4; ++mt)
#pragma unroll
      for (int r = 0; r < 4; ++r) acc[mt][r] *= alpha;
#pragma unroll
    for (int ks = 0; ks < 2; ++ks) {
      const short8 pf =
          *(const short8*)((char*)Plw + l15 * 128 + (((ks * 4 + lg) ^ x7) * 16));
#pragma unroll
      for (int mt = 0; mt < 4; ++mt) {
        const short8 vf =
            *(const short8*)&Vl[(mt * 16 + l15) * 64 + (((ks * 4 + lg) ^ x7) * 8)];
        acc[mt] = __builtin_amdgcn_mfma_f32_16x16x32_bf16(vf, pf, acc[mt], 0, 0, 0);
      }
    }
    __syncthreads();
  }
  const int b = bh >> 4, h = bh & 15;
  const float inv = 1.f / l_run;
  const long obase = ((long)(b * 1024 + qrow)) * 1024 + h * 64;
#pragma unroll
  for (int mt = 0; mt < 4; ++mt) {
    const long o = obase + mt * 16 + lg * 4;
    *(uint32_t*)&Out[o] =
        (uint32_t)f2bf(acc[mt][0] * inv) | ((uint32_t)f2bf(acc[mt][1] * inv) << 16);
    *(uint32_t*)&Out[o + 2] =
        (uint32_t)f2bf(acc[mt][2] * inv) | ((uint32_t)f2bf(acc[mt][3] * inv) << 16);
  }
}

extern "C" void kernel_launch(void* const* d_in, const int* in_sizes, int n_in,
                              void* d_out, int out_size, void* d_ws, size_t ws_size,
                              hipStream_t stream) {
  const float* x     = (const float*)d_in[0];
  const float* rope  = (const float*)d_in[1];
  const float* dte   = (const float*)d_in[2];
  const float* vres  = (const float*)d_in[3];
  const float* Wqkv  = (const float*)d_in[4];
  const float* bqkv  = (const float*)d_in[5];
  const float* Wdt   = (const float*)d_in[6];
  const float* bdt   = (const float*)d_in[7];
  const float* qn_g  = (const float*)d_in[8];
  const float* qn_b  = (const float*)d_in[9];
  const float* kn_g  = (const float*)d_in[10];
  const float* kn_b  = (const float*)d_in[11];
  const float* l1    = (const float*)d_in[12];
  const float* l2    = (const float*)d_in[13];
  const float* Wproj = (const float*)d_in[14];
  const float* bproj = (const float*)d_in[15];
  float* out = (float*)d_out;

  char* ws = (char*)d_ws;
  u16*   A_cat = (u16*)(ws);                    // [4096,2048] bf16
  u16*   W_cat = (u16*)(ws + 16777216);         // [3072,2048] bf16
  u16*   Wp    = (u16*)(ws + 29360128);         // [1024,1024] bf16
  u16*   qkvb  = (u16*)(ws + 31457280);         // [4096,3072] bf16
  u16*   Qb    = (u16*)(ws + 56623104);         // [64,1024,64] bf16
  u16*   Ksw   = (u16*)(ws + 65011712);         // swizzled K
  u16*   VTsw  = (u16*)(ws + 73400320);         // swizzled V^T
  u16*   AO    = (u16*)(ws + 81788928);         // [4096,1024] bf16
  // total ws usage: 90,177,536 bytes

  cvt_cat_bf16<<<2048, 256, 0, stream>>>(x, dte, A_cat, (long)4096 * 2048);
  cvt_cat_bf16<<<2048, 256, 0, stream>>>(Wqkv, Wdt, W_cat, (long)3072 * 2048);
  cvt_bf16<<<1024, 256, 0, stream>>>(Wproj, Wp, (long)1024 * 1024);
  // QKV+dt fused GEMM: 128^2 m97 structure, bf16 out
  gemm_bt_b16<<<dim3(32, 24), 256, 0, stream>>>(A_cat, W_cat, qkvb, bqkv, bdt,
                                                4096, 3072, 2048);
  fuse_qkv2<<<dim3(64, 16), 256, 0, stream>>>(qkvb, vres, rope, qn_g, qn_b, kn_g, kn_b,
                                              l1, l2, Qb, Ksw, VTsw);
  attn_fwd2<<<dim3(64, 16), 256, 0, stream>>>(Qb, Ksw, VTsw, AO);
  gemm_bt<<<dim3(32, 8), 256, 0, stream>>>(AO, Wp, out, bproj, nullptr, 4096, 1024, 1024);
}

// Round 11
// 171.953 us; speedup vs baseline: 1.0065x; 1.0065x over previous
//
#include <hip/hip_runtime.h>
#include <stdint.h>

typedef unsigned short u16;
typedef __attribute__((ext_vector_type(8))) short short8;
typedef __attribute__((ext_vector_type(4))) float f32x4;
typedef __attribute__((ext_vector_type(4))) unsigned short u16x4;
typedef __attribute__((ext_vector_type(4))) unsigned int u32x4;

#define DEVI __device__ __forceinline__

DEVI u16 f2bf(float f) {
  uint32_t u = __builtin_bit_cast(uint32_t, f);
  u += 0x7fffu + ((u >> 16) & 1u);
  return (u16)(u >> 16);
}

DEVI float bf2f(u16 u) {
  uint32_t v = ((uint32_t)u) << 16;
  return __builtin_bit_cast(float, v);
}

DEVI uint32_t cvt_pk_bf16(float lo, float hi) {
  uint32_t r;
  asm("v_cvt_pk_bf16_f32 %0, %1, %2" : "=v"(r) : "v"(lo), "v"(hi));
  return r;
}

DEVI void gload_lds16(const void* g, void* l) {
  __builtin_amdgcn_global_load_lds(
      (const __attribute__((address_space(1))) void*)g,
      (__attribute__((address_space(3))) void*)(uint32_t)(uintptr_t)l,
      16, 0, 0);
}

// ---------------- convert / concat fp32 -> bf16 ----------------
__global__ void cvt_cat_bf16(const float* __restrict__ a, const float* __restrict__ b,
                             u16* __restrict__ dst, long total) {
  for (long i = ((long)blockIdx.x * 256 + threadIdx.x) * 4; i < total;
       i += (long)gridDim.x * 1024) {
    const long row = i >> 11;
    const long c = i & 2047;
    const float* src = (c < 1024) ? (a + row * 1024 + c) : (b + row * 1024 + (c - 1024));
    const float4 v = *(const float4*)src;
    u16x4 o = {f2bf(v.x), f2bf(v.y), f2bf(v.z), f2bf(v.w)};
    *(u16x4*)(dst + i) = o;
  }
}

__global__ void cvt_bf16(const float* __restrict__ a, u16* __restrict__ dst, long total) {
  for (long i = ((long)blockIdx.x * 256 + threadIdx.x) * 4; i < total;
       i += (long)gridDim.x * 1024) {
    const float4 v = *(const float4*)(a + i);
    u16x4 o = {f2bf(v.x), f2bf(v.y), f2bf(v.z), f2bf(v.w)};
    *(u16x4*)(dst + i) = o;
  }
}

// ---------------- bf16 GEMM 128^2 (m97 structure), fp32 out — proj ------------
__global__ __launch_bounds__(256, 2)
void gemm_bt(const u16* __restrict__ A, const u16* __restrict__ B,
             float* __restrict__ C, const float* __restrict__ bias1,
             const float* __restrict__ bias2, int M, int N, int K) {
  __shared__ u16 As[128 * 32];
  __shared__ u16 Bs[128 * 32];
  const int t = threadIdx.x;
  const int w = t >> 6, l = t & 63;
  const int l15 = l & 15, lg = l >> 4;
  const int bm = blockIdx.x, bn = blockIdx.y;
  const int wr = (w >> 1) * 64, wc = (w & 1) * 64;
  f32x4 acc[4][4] = {};
  const int c0 = w * 64 + l;

  for (int kt = 0; kt < (K >> 5); ++kt) {
#pragma unroll
    for (int i = 0; i < 2; ++i) {
      const int c = i * 256 + c0;
      const int row = c >> 2, seg = c & 3;
      gload_lds16(A + (long)(bm * 128 + row) * K + kt * 32 + seg * 8,
                  (char*)As + w * 1024 + i * 4096);
      gload_lds16(B + (long)(bn * 128 + row) * K + kt * 32 + seg * 8,
                  (char*)Bs + w * 1024 + i * 4096);
    }
    __syncthreads();
    short8 af[4], bfr[4];
#pragma unroll
    for (int m = 0; m < 4; ++m)
      af[m] = *(const short8*)&As[(wr + m * 16 + l15) * 32 + lg * 8];
#pragma unroll
    for (int n = 0; n < 4; ++n)
      bfr[n] = *(const short8*)&Bs[(wc + n * 16 + l15) * 32 + lg * 8];
#pragma unroll
    for (int m = 0; m < 4; ++m)
#pragma unroll
      for (int n = 0; n < 4; ++n)
        acc[m][n] = __builtin_amdgcn_mfma_f32_16x16x32_bf16(af[m], bfr[n], acc[m][n], 0, 0, 0);
    __syncthreads();
  }
#pragma unroll
  for (int m = 0; m < 4; ++m) {
    const int row0 = bm * 128 + wr + m * 16 + lg * 4;
#pragma unroll
    for (int n = 0; n < 4; ++n) {
      const int col = bn * 128 + wc + n * 16 + l15;
      float bia = 0.f;
      if (bias1) bia += bias1[col];
      if (bias2) bia += bias2[col];
#pragma unroll
      for (int r = 0; r < 4; ++r)
        C[(long)(row0 + r) * N + col] = acc[m][n][r] + bia;
    }
  }
}

// ---------------- same structure, bf16 out — QKV+dt fused GEMM ----------------
__global__ __launch_bounds__(256, 2)
void gemm_bt_b16(const u16* __restrict__ A, const u16* __restrict__ B,
                 u16* __restrict__ C, const float* __restrict__ bias1,
                 const float* __restrict__ bias2, int M, int N, int K) {
  __shared__ u16 As[128 * 32];
  __shared__ u16 Bs[128 * 32];
  const int t = threadIdx.x;
  const int w = t >> 6, l = t & 63;
  const int l15 = l & 15, lg = l >> 4;
  const int bm = blockIdx.x, bn = blockIdx.y;
  const int wr = (w >> 1) * 64, wc = (w & 1) * 64;
  f32x4 acc[4][4] = {};
  const int c0 = w * 64 + l;

  for (int kt = 0; kt < (K >> 5); ++kt) {
#pragma unroll
    for (int i = 0; i < 2; ++i) {
      const int c = i * 256 + c0;
      const int row = c >> 2, seg = c & 3;
      gload_lds16(A + (long)(bm * 128 + row) * K + kt * 32 + seg * 8,
                  (char*)As + w * 1024 + i * 4096);
      gload_lds16(B + (long)(bn * 128 + row) * K + kt * 32 + seg * 8,
                  (char*)Bs + w * 1024 + i * 4096);
    }
    __syncthreads();
    short8 af[4], bfr[4];
#pragma unroll
    for (int m = 0; m < 4; ++m)
      af[m] = *(const short8*)&As[(wr + m * 16 + l15) * 32 + lg * 8];
#pragma unroll
    for (int n = 0; n < 4; ++n)
      bfr[n] = *(const short8*)&Bs[(wc + n * 16 + l15) * 32 + lg * 8];
#pragma unroll
    for (int m = 0; m < 4; ++m)
#pragma unroll
      for (int n = 0; n < 4; ++n)
        acc[m][n] = __builtin_amdgcn_mfma_f32_16x16x32_bf16(af[m], bfr[n], acc[m][n], 0, 0, 0);
    __syncthreads();
  }
#pragma unroll
  for (int m = 0; m < 4; ++m) {
    const int row0 = bm * 128 + wr + m * 16 + lg * 4;
#pragma unroll
    for (int n = 0; n < 4; ++n) {
      const int col = bn * 128 + wc + n * 16 + l15;
      float bia = 0.f;
      if (bias1) bia += bias1[col];
      if (bias2) bia += bias2[col];
#pragma unroll
      for (int r = 0; r < 4; ++r)
        C[(long)(row0 + r) * N + col] = f2bf(acc[m][n][r] + bia);
    }
  }
}

// ---------------- fuse: split qkv (bf16), vres mix, LN(q,k), RoPE ----------------
__global__ __launch_bounds__(256)
void fuse_qkv2(const u16* __restrict__ qkv, const float* __restrict__ vres,
               const float* __restrict__ rope,
               const float* __restrict__ qg, const float* __restrict__ qb,
               const float* __restrict__ kg, const float* __restrict__ kb,
               const float* __restrict__ pl1, const float* __restrict__ pl2,
               u16* __restrict__ Q, u16* __restrict__ Ksw, u16* __restrict__ VTsw) {
  __shared__ u16 Vl[64][72];
  const int t = threadIdx.x, w = t >> 6, d = t & 63;
  const int bh = blockIdx.x, ntile = blockIdx.y;
  const int b = bh >> 4, h = bh & 15, n0 = ntile * 64;
  const float l1 = pl1[0], l2 = pl2[0];
  const float gq = qg[d], bq = qb[d];
  const float gk = kg[d], bk = kb[d];
  const float sgn = (d < 32) ? -1.f : 1.f;
  const int c = d >> 3, d7 = d & 7;

  for (int i = 0; i < 16; ++i) {
    const int nl = w * 16 + i;
    const int n = n0 + nl;
    const long base = ((long)(b * 1024 + n)) * 3072 + h * 64 + d;
    float q = bf2f(qkv[base]);
    float k = bf2f(qkv[base + 1024]);
    float v = bf2f(qkv[base + 2048]);
    v = l1 * v + l2 * vres[((long)(bh * 1024 + n)) * 64 + d];
    const float sinv = rope[n * 128 + d];
    const float cosv = rope[n * 128 + 64 + d];
    float s = q;
#pragma unroll
    for (int off = 1; off < 64; off <<= 1) s += __shfl_xor(s, off);
    const float qc = q - s * (1.f / 64.f);
    float vs = qc * qc;
#pragma unroll
    for (int off = 1; off < 64; off <<= 1) vs += __shfl_xor(vs, off);
    const float qn = qc * (1.f / sqrtf(vs * (1.f / 64.f) + 1e-5f)) * gq + bq;
    float s2 = k;
#pragma unroll
    for (int off = 1; off < 64; off <<= 1) s2 += __shfl_xor(s2, off);
    const float kc = k - s2 * (1.f / 64.f);
    float vs2 = kc * kc;
#pragma unroll
    for (int off = 1; off < 64; off <<= 1) vs2 += __shfl_xor(vs2, off);
    const float kn = kc * (1.f / sqrtf(vs2 * (1.f / 64.f) + 1e-5f)) * gk + bk;
    const float qo = __shfl_xor(qn, 32);
    const float ko = __shfl_xor(kn, 32);
    const float qr = qn * cosv + sgn * qo * sinv;
    const float kr = kn * cosv + sgn * ko * sinv;
    Q[(long)bh * 65536 + (long)n * 64 + d] = f2bf(qr);
    Ksw[(long)bh * 65536 + (long)n * 64 + ((c ^ (n & 7)) * 8 + d7)] = f2bf(kr);
    Vl[nl][d] = f2bf(v);
  }
  __syncthreads();
#pragma unroll
  for (int i = 0; i < 2; ++i) {
    const int task = i * 256 + t;
    const int dd = task >> 3, cc = task & 7;
    short8 o;
#pragma unroll
    for (int u = 0; u < 8; ++u) o[u] = (short)Vl[cc * 8 + u][dd];
    *(short8*)&VTsw[((long)(bh * 64 + dd)) * 1024 + n0 + ((cc ^ (dd & 7)) * 8)] = o;
  }
}

// -------- flash attention fwd v7: fwd2 skeleton + in-register P (no P LDS) ----
// P regrouping (verified mapping): source lane (q=l15, lg) reg (mt,r) holds
// P[k=16mt+4lg+r][q]. PV B-operand lane (q, lg) needs k = 32ks+8lg+j, j=0..7.
// Build via: pack pairs (cvt_pk) -> u0/u1[mt]; per ks:
// (X,Y) = permlane32_swap(u[2ks], u[2ks+1]) gives X = lo-half sources,
// Y = hi-half sources; dword j01 = hi?shfl16(Y):X, j45 = hi?Y:shfl16(X).
__global__ __launch_bounds__(256, 4)
void attn_fwd7(const u16* __restrict__ Q, const u16* __restrict__ Ksw,
               const u16* __restrict__ VTsw, u16* __restrict__ Out) {
  __shared__ u16 Kl[64 * 64];
  __shared__ u16 Vl[64 * 64];
  const int t = threadIdx.x, w = t >> 6, l = t & 63;
  const int l15 = l & 15, lg = l >> 4;
  const int x7 = l15 & 7;
  const int bh = blockIdx.x, q0 = blockIdx.y * 64;
  const long bo = (long)bh * 65536;
  const bool hihalf = (l & 16) != 0;

  const int qrow = q0 + w * 16 + l15;
  short8 qf[2];
#pragma unroll
  for (int ks = 0; ks < 2; ++ks)
    qf[ks] = *(const short8*)&Q[bo + (long)qrow * 64 + ks * 32 + lg * 8];

  f32x4 acc[4] = {};
  float m_run = -1e30f, l_run = 0.f;

  for (int kv = 0; kv < 16; ++kv) {
    const int kvb = kv * 64;
#pragma unroll
    for (int i = 0; i < 2; ++i) {
      const int idx = i * 256 + t;
      const int row = idx >> 3, seg = idx & 7;
      gload_lds16(Ksw + bo + (long)(kvb + row) * 64 + seg * 8, (char*)Kl + idx * 16);
      gload_lds16(VTsw + bo + (long)row * 1024 + kvb + seg * 8, (char*)Vl + idx * 16);
    }
    __syncthreads();
    f32x4 p[4];
#pragma unroll
    for (int mt = 0; mt < 4; ++mt) {
      f32x4 ps = {};
#pragma unroll
      for (int ks = 0; ks < 2; ++ks) {
        const short8 kf =
            *(const short8*)&Kl[(mt * 16 + l15) * 64 + (((ks * 4 + lg) ^ x7) * 8)];
        ps = __builtin_amdgcn_mfma_f32_16x16x32_bf16(kf, qf[ks], ps, 0, 0, 0);
      }
      p[mt] = ps;
    }
    float mx = p[0][0];
#pragma unroll
    for (int mt = 0; mt < 4; ++mt)
#pragma unroll
      for (int r = 0; r < 4; ++r) mx = fmaxf(mx, p[mt][r]);
    mx = fmaxf(mx, __shfl_xor(mx, 16));
    mx = fmaxf(mx, __shfl_xor(mx, 32));
    const float mnew = fmaxf(m_run, mx * 0.125f);
    const float alpha = __expf(m_run - mnew);
    m_run = mnew;
    float sum = 0.f;
#pragma unroll
    for (int mt = 0; mt < 4; ++mt)
#pragma unroll
      for (int r = 0; r < 4; ++r) {
        const float e = __expf(p[mt][r] * 0.125f - mnew);
        p[mt][r] = e;
        sum += e;
      }
    sum += __shfl_xor(sum, 16);
    sum += __shfl_xor(sum, 32);
    l_run = l_run * alpha + sum;
    // pack P to bf16 pairs in-register
    uint32_t u0[4], u1[4];
#pragma unroll
    for (int mt = 0; mt < 4; ++mt) {
      u0[mt] = cvt_pk_bf16(p[mt][0], p[mt][1]);
      u1[mt] = cvt_pk_bf16(p[mt][2], p[mt][3]);
    }
    // rescale O^T
#pragma unroll
    for (int mt = 0; mt < 4; ++mt)
#pragma unroll
      for (int r = 0; r < 4; ++r) acc[mt][r] *= alpha;
    // O^T += mfma(V^T, P): build B-operand per ks via permlane exchange
#pragma unroll
    for (int ks = 0; ks < 2; ++ks) {
      uint32_t X0 = u0[2 * ks], Y0 = u0[2 * ks + 1];
      asm("v_permlane32_swap_b32 %0, %1" : "+v"(X0), "+v"(Y0));
      uint32_t X1 = u1[2 * ks], Y1 = u1[2 * ks + 1];
      asm("v_permlane32_swap_b32 %0, %1" : "+v"(X1), "+v"(Y1));
      const uint32_t Xs0 = (uint32_t)__shfl_xor((int)X0, 16);
      const uint32_t Ys0 = (uint32_t)__shfl_xor((int)Y0, 16);
      const uint32_t Xs1 = (uint32_t)__shfl_xor((int)X1, 16);
      const uint32_t Ys1 = (uint32_t)__shfl_xor((int)Y1, 16);
      u32x4 pv;
      pv[0] = hihalf ? Ys0 : X0;   // k j=0,1
      pv[1] = hihalf ? Ys1 : X1;   // k j=2,3
      pv[2] = hihalf ? Y0 : Xs0;   // k j=4,5
      pv[3] = hihalf ? Y1 : Xs1;   // k j=6,7
      const short8 pf = __builtin_bit_cast(short8, pv);
#pragma unroll
      for (int mt = 0; mt < 4; ++mt) {
        const short8 vf =
            *(const short8*)&Vl[(mt * 16 + l15) * 64 + (((ks * 4 + lg) ^ x7) * 8)];
        acc[mt] = __builtin_amdgcn_mfma_f32_16x16x32_bf16(vf, pf, acc[mt], 0, 0, 0);
      }
    }
    __syncthreads();
  }
  const int b = bh >> 4, h = bh & 15;
  const float inv = 1.f / l_run;
  const long obase = ((long)(b * 1024 + qrow)) * 1024 + h * 64;
#pragma unroll
  for (int mt = 0; mt < 4; ++mt) {
    const long o = obase + mt * 16 + lg * 4;
    *(uint32_t*)&Out[o] =
        (uint32_t)f2bf(acc[mt][0] * inv) | ((uint32_t)f2bf(acc[mt][1] * inv) << 16);
    *(uint32_t*)&Out[o + 2] =
        (uint32_t)f2bf(acc[mt][2] * inv) | ((uint32_t)f2bf(acc[mt][3] * inv) << 16);
  }
}

extern "C" void kernel_launch(void* const* d_in, const int* in_sizes, int n_in,
                              void* d_out, int out_size, void* d_ws, size_t ws_size,
                              hipStream_t stream) {
  const float* x     = (const float*)d_in[0];
  const float* rope  = (const float*)d_in[1];
  const float* dte   = (const float*)d_in[2];
  const float* vres  = (const float*)d_in[3];
  const float* Wqkv  = (const float*)d_in[4];
  const float* bqkv  = (const float*)d_in[5];
  const float* Wdt   = (const float*)d_in[6];
  const float* bdt   = (const float*)d_in[7];
  const float* qn_g  = (const float*)d_in[8];
  const float* qn_b  = (const float*)d_in[9];
  const float* kn_g  = (const float*)d_in[10];
  const float* kn_b  = (const float*)d_in[11];
  const float* l1    = (const float*)d_in[12];
  const float* l2    = (const float*)d_in[13];
  const float* Wproj = (const float*)d_in[14];
  const float* bproj = (const float*)d_in[15];
  float* out = (float*)d_out;

  char* ws = (char*)d_ws;
  u16*   A_cat = (u16*)(ws);                    // [4096,2048] bf16
  u16*   W_cat = (u16*)(ws + 16777216);         // [3072,2048] bf16
  u16*   Wp    = (u16*)(ws + 29360128);         // [1024,1024] bf16
  u16*   qkvb  = (u16*)(ws + 31457280);         // [4096,3072] bf16
  u16*   Qb    = (u16*)(ws + 56623104);         // [64,1024,64] bf16
  u16*   Ksw   = (u16*)(ws + 65011712);         // swizzled K
  u16*   VTsw  = (u16*)(ws + 73400320);         // swizzled V^T
  u16*   AO    = (u16*)(ws + 81788928);         // [4096,1024] bf16
  // total ws usage: 90,177,536 bytes

  cvt_cat_bf16<<<2048, 256, 0, stream>>>(x, dte, A_cat, (long)4096 * 2048);
  cvt_cat_bf16<<<2048, 256, 0, stream>>>(Wqkv, Wdt, W_cat, (long)3072 * 2048);
  cvt_bf16<<<1024, 256, 0, stream>>>(Wproj, Wp, (long)1024 * 1024);
  // QKV+dt fused GEMM: 128^2 m97 structure, bf16 out
  gemm_bt_b16<<<dim3(32, 24), 256, 0, stream>>>(A_cat, W_cat, qkvb, bqkv, bdt,
                                                4096, 3072, 2048);
  fuse_qkv2<<<dim3(64, 16), 256, 0, stream>>>(qkvb, vres, rope, qn_g, qn_b, kn_g, kn_b,
                                              l1, l2, Qb, Ksw, VTsw);
  attn_fwd7<<<dim3(64, 16), 256, 0, stream>>>(Qb, Ksw, VTsw, AO);
  gemm_bt<<<dim3(32, 8), 256, 0, stream>>>(AO, Wp, out, bproj, nullptr, 4096, 1024, 1024);
}

// Round 12
// 167.842 us; speedup vs baseline: 1.0312x; 1.0245x over previous
//
#include <hip/hip_runtime.h>
#include <stdint.h>

typedef unsigned short u16;
typedef __attribute__((ext_vector_type(8))) short short8;
typedef __attribute__((ext_vector_type(4))) float f32x4;
typedef __attribute__((ext_vector_type(4))) unsigned short u16x4;
typedef __attribute__((ext_vector_type(4))) unsigned int u32x4;

#define DEVI __device__ __forceinline__

DEVI u16 f2bf(float f) {
  uint32_t u = __builtin_bit_cast(uint32_t, f);
  u += 0x7fffu + ((u >> 16) & 1u);
  return (u16)(u >> 16);
}

DEVI float bf2f(u16 u) {
  uint32_t v = ((uint32_t)u) << 16;
  return __builtin_bit_cast(float, v);
}

DEVI uint32_t cvt_pk_bf16(float lo, float hi) {
  uint32_t r;
  asm("v_cvt_pk_bf16_f32 %0, %1, %2" : "=v"(r) : "v"(lo), "v"(hi));
  return r;
}

DEVI void gload_lds16(const void* g, void* l) {
  __builtin_amdgcn_global_load_lds(
      (const __attribute__((address_space(1))) void*)g,
      (__attribute__((address_space(3))) void*)(uint32_t)(uintptr_t)l,
      16, 0, 0);
}

// ---------------- merged convert: A_cat, W_cat, Wp in one sweep ----------------
__global__ void cvt_all(const float* __restrict__ x, const float* __restrict__ dte,
                        const float* __restrict__ Wqkv, const float* __restrict__ Wdt,
                        const float* __restrict__ Wproj,
                        u16* __restrict__ A_cat, u16* __restrict__ W_cat,
                        u16* __restrict__ Wp) {
  const long T0 = (long)4096 * 2048 / 4;  // A_cat vec4 tasks
  const long T1 = (long)3072 * 2048 / 4;  // W_cat vec4 tasks
  const long T2 = (long)1024 * 1024 / 4;  // Wp vec4 tasks
  for (long v = (long)blockIdx.x * 256 + threadIdx.x; v < T0 + T1 + T2;
       v += (long)gridDim.x * 256) {
    const float* src;
    u16* dst;
    if (v < T0) {
      const long i = v * 4;
      const long row = i >> 11, c = i & 2047;
      src = (c < 1024) ? (x + row * 1024 + c) : (dte + row * 1024 + (c - 1024));
      dst = A_cat + i;
    } else if (v < T0 + T1) {
      const long i = (v - T0) * 4;
      const long row = i >> 11, c = i & 2047;
      src = (c < 1024) ? (Wqkv + row * 1024 + c) : (Wdt + row * 1024 + (c - 1024));
      dst = W_cat + i;
    } else {
      const long i = (v - T0 - T1) * 4;
      src = Wproj + i;
      dst = Wp + i;
    }
    const float4 f = *(const float4*)src;
    u16x4 o = {f2bf(f.x), f2bf(f.y), f2bf(f.z), f2bf(f.w)};
    *(u16x4*)dst = o;
  }
}

// ---------------- bf16 GEMM 128^2 (m97 structure), fp32 out — proj ------------
__global__ __launch_bounds__(256, 2)
void gemm_bt(const u16* __restrict__ A, const u16* __restrict__ B,
             float* __restrict__ C, const float* __restrict__ bias1,
             const float* __restrict__ bias2, int M, int N, int K) {
  __shared__ u16 As[128 * 32];
  __shared__ u16 Bs[128 * 32];
  const int t = threadIdx.x;
  const int w = t >> 6, l = t & 63;
  const int l15 = l & 15, lg = l >> 4;
  const int bm = blockIdx.x, bn = blockIdx.y;
  const int wr = (w >> 1) * 64, wc = (w & 1) * 64;
  f32x4 acc[4][4] = {};
  const int c0 = w * 64 + l;

  for (int kt = 0; kt < (K >> 5); ++kt) {
#pragma unroll
    for (int i = 0; i < 2; ++i) {
      const int c = i * 256 + c0;
      const int row = c >> 2, seg = c & 3;
      gload_lds16(A + (long)(bm * 128 + row) * K + kt * 32 + seg * 8,
                  (char*)As + w * 1024 + i * 4096);
      gload_lds16(B + (long)(bn * 128 + row) * K + kt * 32 + seg * 8,
                  (char*)Bs + w * 1024 + i * 4096);
    }
    __syncthreads();
    short8 af[4], bfr[4];
#pragma unroll
    for (int m = 0; m < 4; ++m)
      af[m] = *(const short8*)&As[(wr + m * 16 + l15) * 32 + lg * 8];
#pragma unroll
    for (int n = 0; n < 4; ++n)
      bfr[n] = *(const short8*)&Bs[(wc + n * 16 + l15) * 32 + lg * 8];
#pragma unroll
    for (int m = 0; m < 4; ++m)
#pragma unroll
      for (int n = 0; n < 4; ++n)
        acc[m][n] = __builtin_amdgcn_mfma_f32_16x16x32_bf16(af[m], bfr[n], acc[m][n], 0, 0, 0);
    __syncthreads();
  }
#pragma unroll
  for (int m = 0; m < 4; ++m) {
    const int row0 = bm * 128 + wr + m * 16 + lg * 4;
#pragma unroll
    for (int n = 0; n < 4; ++n) {
      const int col = bn * 128 + wc + n * 16 + l15;
      float bia = 0.f;
      if (bias1) bia += bias1[col];
      if (bias2) bia += bias2[col];
#pragma unroll
      for (int r = 0; r < 4; ++r)
        C[(long)(row0 + r) * N + col] = acc[m][n][r] + bia;
    }
  }
}

// ---------------- same structure, bf16 out — QKV+dt fused GEMM ----------------
__global__ __launch_bounds__(256, 2)
void gemm_bt_b16(const u16* __restrict__ A, const u16* __restrict__ B,
                 u16* __restrict__ C, const float* __restrict__ bias1,
                 const float* __restrict__ bias2, int M, int N, int K) {
  __shared__ u16 As[128 * 32];
  __shared__ u16 Bs[128 * 32];
  const int t = threadIdx.x;
  const int w = t >> 6, l = t & 63;
  const int l15 = l & 15, lg = l >> 4;
  const int bm = blockIdx.x, bn = blockIdx.y;
  const int wr = (w >> 1) * 64, wc = (w & 1) * 64;
  f32x4 acc[4][4] = {};
  const int c0 = w * 64 + l;

  for (int kt = 0; kt < (K >> 5); ++kt) {
#pragma unroll
    for (int i = 0; i < 2; ++i) {
      const int c = i * 256 + c0;
      const int row = c >> 2, seg = c & 3;
      gload_lds16(A + (long)(bm * 128 + row) * K + kt * 32 + seg * 8,
                  (char*)As + w * 1024 + i * 4096);
      gload_lds16(B + (long)(bn * 128 + row) * K + kt * 32 + seg * 8,
                  (char*)Bs + w * 1024 + i * 4096);
    }
    __syncthreads();
    short8 af[4], bfr[4];
#pragma unroll
    for (int m = 0; m < 4; ++m)
      af[m] = *(const short8*)&As[(wr + m * 16 + l15) * 32 + lg * 8];
#pragma unroll
    for (int n = 0; n < 4; ++n)
      bfr[n] = *(const short8*)&Bs[(wc + n * 16 + l15) * 32 + lg * 8];
#pragma unroll
    for (int m = 0; m < 4; ++m)
#pragma unroll
      for (int n = 0; n < 4; ++n)
        acc[m][n] = __builtin_amdgcn_mfma_f32_16x16x32_bf16(af[m], bfr[n], acc[m][n], 0, 0, 0);
    __syncthreads();
  }
#pragma unroll
  for (int m = 0; m < 4; ++m) {
    const int row0 = bm * 128 + wr + m * 16 + lg * 4;
#pragma unroll
    for (int n = 0; n < 4; ++n) {
      const int col = bn * 128 + wc + n * 16 + l15;
      float bia = 0.f;
      if (bias1) bia += bias1[col];
      if (bias2) bia += bias2[col];
#pragma unroll
      for (int r = 0; r < 4; ++r)
        C[(long)(row0 + r) * N + col] = f2bf(acc[m][n][r] + bia);
    }
  }
}

// ---------------- fuse: split qkv (bf16), vres mix, LN(q,k), RoPE ----------------
__global__ __launch_bounds__(256)
void fuse_qkv2(const u16* __restrict__ qkv, const float* __restrict__ vres,
               const float* __restrict__ rope,
               const float* __restrict__ qg, const float* __restrict__ qb,
               const float* __restrict__ kg, const float* __restrict__ kb,
               const float* __restrict__ pl1, const float* __restrict__ pl2,
               u16* __restrict__ Q, u16* __restrict__ Ksw, u16* __restrict__ VTsw) {
  __shared__ u16 Vl[64][72];
  const int t = threadIdx.x, w = t >> 6, d = t & 63;
  const int bh = blockIdx.x, ntile = blockIdx.y;
  const int b = bh >> 4, h = bh & 15, n0 = ntile * 64;
  const float l1 = pl1[0], l2 = pl2[0];
  const float gq = qg[d], bq = qb[d];
  const float gk = kg[d], bk = kb[d];
  const float sgn = (d < 32) ? -1.f : 1.f;
  const int c = d >> 3, d7 = d & 7;

  for (int i = 0; i < 16; ++i) {
    const int nl = w * 16 + i;
    const int n = n0 + nl;
    const long base = ((long)(b * 1024 + n)) * 3072 + h * 64 + d;
    float q = bf2f(qkv[base]);
    float k = bf2f(qkv[base + 1024]);
    float v = bf2f(qkv[base + 2048]);
    v = l1 * v + l2 * vres[((long)(bh * 1024 + n)) * 64 + d];
    const float sinv = rope[n * 128 + d];
    const float cosv = rope[n * 128 + 64 + d];
    float s = q;
#pragma unroll
    for (int off = 1; off < 64; off <<= 1) s += __shfl_xor(s, off);
    const float qc = q - s * (1.f / 64.f);
    float vs = qc * qc;
#pragma unroll
    for (int off = 1; off < 64; off <<= 1) vs += __shfl_xor(vs, off);
    const float qn = qc * (1.f / sqrtf(vs * (1.f / 64.f) + 1e-5f)) * gq + bq;
    float s2 = k;
#pragma unroll
    for (int off = 1; off < 64; off <<= 1) s2 += __shfl_xor(s2, off);
    const float kc = k - s2 * (1.f / 64.f);
    float vs2 = kc * kc;
#pragma unroll
    for (int off = 1; off < 64; off <<= 1) vs2 += __shfl_xor(vs2, off);
    const float kn = kc * (1.f / sqrtf(vs2 * (1.f / 64.f) + 1e-5f)) * gk + bk;
    const float qo = __shfl_xor(qn, 32);
    const float ko = __shfl_xor(kn, 32);
    const float qr = qn * cosv + sgn * qo * sinv;
    const float kr = kn * cosv + sgn * ko * sinv;
    Q[(long)bh * 65536 + (long)n * 64 + d] = f2bf(qr);
    Ksw[(long)bh * 65536 + (long)n * 64 + ((c ^ (n & 7)) * 8 + d7)] = f2bf(kr);
    Vl[nl][d] = f2bf(v);
  }
  __syncthreads();
#pragma unroll
  for (int i = 0; i < 2; ++i) {
    const int task = i * 256 + t;
    const int dd = task >> 3, cc = task & 7;
    short8 o;
#pragma unroll
    for (int u = 0; u < 8; ++u) o[u] = (short)Vl[cc * 8 + u][dd];
    *(short8*)&VTsw[((long)(bh * 64 + dd)) * 1024 + n0 + ((cc ^ (dd & 7)) * 8)] = o;
  }
}

// -------- flash attention fwd v8: fwd7 (in-register P) + KVBLK=128 staging ----
// Same single-buffer skeleton as fwd2/fwd7 (stage -> __syncthreads -> compute
// -> __syncthreads) but 128 kv rows staged per barrier period with two 64-row
// compute bodies inside: barrier count halves, drain cost amortizes.
// LDS: Kl[128][64] 16KB + Vl[64][128] 16KB = 32KB -> 4 blocks/CU.
__global__ __launch_bounds__(256, 4)
void attn_fwd8(const u16* __restrict__ Q, const u16* __restrict__ Ksw,
               const u16* __restrict__ VTsw, u16* __restrict__ Out) {
  __shared__ u16 Kl[128 * 64];
  __shared__ u16 Vl[64 * 128];
  const int t = threadIdx.x, w = t >> 6, l = t & 63;
  const int l15 = l & 15, lg = l >> 4;
  const int x7 = l15 & 7;
  const int bh = blockIdx.x, q0 = blockIdx.y * 64;
  const long bo = (long)bh * 65536;
  const bool hihalf = (l & 16) != 0;

  const int qrow = q0 + w * 16 + l15;
  short8 qf[2];
#pragma unroll
  for (int ks = 0; ks < 2; ++ks)
    qf[ks] = *(const short8*)&Q[bo + (long)qrow * 64 + ks * 32 + lg * 8];

  f32x4 acc[4] = {};
  float m_run = -1e30f, l_run = 0.f;

  for (int kb = 0; kb < 8; ++kb) {
    const int kvb = kb * 128;
    // stage 128 K rows + V^T cols [kvb, kvb+128) — verbatim (pre-swizzled)
#pragma unroll
    for (int i = 0; i < 4; ++i) {
      const int idx = i * 256 + t;             // 0..1023
      const int krow = idx >> 3, kseg = idx & 7;
      gload_lds16(Ksw + bo + (long)(kvb + krow) * 64 + kseg * 8, (char*)Kl + idx * 16);
      const int vd = idx >> 4, vc = idx & 15;  // d row, 16B chunk in 128 cols
      gload_lds16(VTsw + bo + (long)vd * 1024 + kvb + vc * 8,
                  (char*)Vl + vd * 256 + vc * 16);
    }
    __syncthreads();
#pragma unroll
    for (int tb = 0; tb < 2; ++tb) {
      f32x4 p[4];
#pragma unroll
      for (int mt = 0; mt < 4; ++mt) {
        f32x4 ps = {};
#pragma unroll
        for (int ks = 0; ks < 2; ++ks) {
          const short8 kf = *(const short8*)&Kl[(tb * 64 + mt * 16 + l15) * 64 +
                                                (((ks * 4 + lg) ^ x7) * 8)];
          ps = __builtin_amdgcn_mfma_f32_16x16x32_bf16(kf, qf[ks], ps, 0, 0, 0);
        }
        p[mt] = ps;
      }
      float mx = p[0][0];
#pragma unroll
      for (int mt = 0; mt < 4; ++mt)
#pragma unroll
        for (int r = 0; r < 4; ++r) mx = fmaxf(mx, p[mt][r]);
      mx = fmaxf(mx, __shfl_xor(mx, 16));
      mx = fmaxf(mx, __shfl_xor(mx, 32));
      const float mnew = fmaxf(m_run, mx * 0.125f);
      const float alpha = __expf(m_run - mnew);
      m_run = mnew;
      float sum = 0.f;
#pragma unroll
      for (int mt = 0; mt < 4; ++mt)
#pragma unroll
        for (int r = 0; r < 4; ++r) {
          const float e = __expf(p[mt][r] * 0.125f - mnew);
          p[mt][r] = e;
          sum += e;
        }
      sum += __shfl_xor(sum, 16);
      sum += __shfl_xor(sum, 32);
      l_run = l_run * alpha + sum;
      uint32_t u0[4], u1[4];
#pragma unroll
      for (int mt = 0; mt < 4; ++mt) {
        u0[mt] = cvt_pk_bf16(p[mt][0], p[mt][1]);
        u1[mt] = cvt_pk_bf16(p[mt][2], p[mt][3]);
      }
#pragma unroll
      for (int mt = 0; mt < 4; ++mt)
#pragma unroll
        for (int r = 0; r < 4; ++r) acc[mt][r] *= alpha;
#pragma unroll
      for (int ks = 0; ks < 2; ++ks) {
        uint32_t X0 = u0[2 * ks], Y0 = u0[2 * ks + 1];
        asm("v_permlane32_swap_b32 %0, %1" : "+v"(X0), "+v"(Y0));
        uint32_t X1 = u1[2 * ks], Y1 = u1[2 * ks + 1];
        asm("v_permlane32_swap_b32 %0, %1" : "+v"(X1), "+v"(Y1));
        const uint32_t Xs0 = (uint32_t)__shfl_xor((int)X0, 16);
        const uint32_t Ys0 = (uint32_t)__shfl_xor((int)Y0, 16);
        const uint32_t Xs1 = (uint32_t)__shfl_xor((int)X1, 16);
        const uint32_t Ys1 = (uint32_t)__shfl_xor((int)Y1, 16);
        u32x4 pv;
        pv[0] = hihalf ? Ys0 : X0;
        pv[1] = hihalf ? Ys1 : X1;
        pv[2] = hihalf ? Y0 : Xs0;
        pv[3] = hihalf ? Y1 : Xs1;
        const short8 pf = __builtin_bit_cast(short8, pv);
#pragma unroll
        for (int mt = 0; mt < 4; ++mt) {
          const short8 vf = *(const short8*)&Vl[(mt * 16 + l15) * 128 + tb * 64 +
                                                (((ks * 4 + lg) ^ x7) * 8)];
          acc[mt] = __builtin_amdgcn_mfma_f32_16x16x32_bf16(vf, pf, acc[mt], 0, 0, 0);
        }
      }
    }
    __syncthreads();
  }
  const int b = bh >> 4, h = bh & 15;
  const float inv = 1.f / l_run;
  const long obase = ((long)(b * 1024 + qrow)) * 1024 + h * 64;
#pragma unroll
  for (int mt = 0; mt < 4; ++mt) {
    const long o = obase + mt * 16 + lg * 4;
    *(uint32_t*)&Out[o] =
        (uint32_t)f2bf(acc[mt][0] * inv) | ((uint32_t)f2bf(acc[mt][1] * inv) << 16);
    *(uint32_t*)&Out[o + 2] =
        (uint32_t)f2bf(acc[mt][2] * inv) | ((uint32_t)f2bf(acc[mt][3] * inv) << 16);
  }
}

extern "C" void kernel_launch(void* const* d_in, const int* in_sizes, int n_in,
                              void* d_out, int out_size, void* d_ws, size_t ws_size,
                              hipStream_t stream) {
  const float* x     = (const float*)d_in[0];
  const float* rope  = (const float*)d_in[1];
  const float* dte   = (const float*)d_in[2];
  const float* vres  = (const float*)d_in[3];
  const float* Wqkv  = (const float*)d_in[4];
  const float* bqkv  = (const float*)d_in[5];
  const float* Wdt   = (const float*)d_in[6];
  const float* bdt   = (const float*)d_in[7];
  const float* qn_g  = (const float*)d_in[8];
  const float* qn_b  = (const float*)d_in[9];
  const float* kn_g  = (const float*)d_in[10];
  const float* kn_b  = (const float*)d_in[11];
  const float* l1    = (const float*)d_in[12];
  const float* l2    = (const float*)d_in[13];
  const float* Wproj = (const float*)d_in[14];
  const float* bproj = (const float*)d_in[15];
  float* out = (float*)d_out;

  char* ws = (char*)d_ws;
  u16*   A_cat = (u16*)(ws);                    // [4096,2048] bf16
  u16*   W_cat = (u16*)(ws + 16777216);         // [3072,2048] bf16
  u16*   Wp    = (u16*)(ws + 29360128);         // [1024,1024] bf16
  u16*   qkvb  = (u16*)(ws + 31457280);         // [4096,3072] bf16
  u16*   Qb    = (u16*)(ws + 56623104);         // [64,1024,64] bf16
  u16*   Ksw   = (u16*)(ws + 65011712);         // swizzled K
  u16*   VTsw  = (u16*)(ws + 73400320);         // swizzled V^T
  u16*   AO    = (u16*)(ws + 81788928);         // [4096,1024] bf16
  // total ws usage: 90,177,536 bytes

  cvt_all<<<2048, 256, 0, stream>>>(x, dte, Wqkv, Wdt, Wproj, A_cat, W_cat, Wp);
  // QKV+dt fused GEMM: 128^2 m97 structure, bf16 out
  gemm_bt_b16<<<dim3(32, 24), 256, 0, stream>>>(A_cat, W_cat, qkvb, bqkv, bdt,
                                                4096, 3072, 2048);
  fuse_qkv2<<<dim3(64, 16), 256, 0, stream>>>(qkvb, vres, rope, qn_g, qn_b, kn_g, kn_b,
                                              l1, l2, Qb, Ksw, VTsw);
  attn_fwd8<<<dim3(64, 16), 256, 0, stream>>>(Qb, Ksw, VTsw, AO);
  gemm_bt<<<dim3(32, 8), 256, 0, stream>>>(AO, Wp, out, bproj, nullptr, 4096, 1024, 1024);
}

// Round 13
// 165.774 us; speedup vs baseline: 1.0440x; 1.0125x over previous
//
#include <hip/hip_runtime.h>
#include <stdint.h>

typedef unsigned short u16;
typedef __attribute__((ext_vector_type(8))) short short8;
typedef __attribute__((ext_vector_type(4))) float f32x4;
typedef __attribute__((ext_vector_type(4))) unsigned short u16x4;
typedef __attribute__((ext_vector_type(4))) unsigned int u32x4;

#define DEVI __device__ __forceinline__

DEVI u16 f2bf(float f) {
  uint32_t u = __builtin_bit_cast(uint32_t, f);
  u += 0x7fffu + ((u >> 16) & 1u);
  return (u16)(u >> 16);
}

DEVI float bf2f(u16 u) {
  uint32_t v = ((uint32_t)u) << 16;
  return __builtin_bit_cast(float, v);
}

DEVI uint32_t cvt_pk_bf16(float lo, float hi) {
  uint32_t r;
  asm("v_cvt_pk_bf16_f32 %0, %1, %2" : "=v"(r) : "v"(lo), "v"(hi));
  return r;
}

DEVI void gload_lds16(const void* g, void* l) {
  __builtin_amdgcn_global_load_lds(
      (const __attribute__((address_space(1))) void*)g,
      (__attribute__((address_space(3))) void*)(uint32_t)(uintptr_t)l,
      16, 0, 0);
}

// ---------------- merged convert: A_cat, W_cat, Wp in one sweep ----------------
__global__ void cvt_all(const float* __restrict__ x, const float* __restrict__ dte,
                        const float* __restrict__ Wqkv, const float* __restrict__ Wdt,
                        const float* __restrict__ Wproj,
                        u16* __restrict__ A_cat, u16* __restrict__ W_cat,
                        u16* __restrict__ Wp) {
  const long T0 = (long)4096 * 2048 / 4;
  const long T1 = (long)3072 * 2048 / 4;
  const long T2 = (long)1024 * 1024 / 4;
  for (long v = (long)blockIdx.x * 256 + threadIdx.x; v < T0 + T1 + T2;
       v += (long)gridDim.x * 256) {
    const float* src;
    u16* dst;
    if (v < T0) {
      const long i = v * 4;
      const long row = i >> 11, c = i & 2047;
      src = (c < 1024) ? (x + row * 1024 + c) : (dte + row * 1024 + (c - 1024));
      dst = A_cat + i;
    } else if (v < T0 + T1) {
      const long i = (v - T0) * 4;
      const long row = i >> 11, c = i & 2047;
      src = (c < 1024) ? (Wqkv + row * 1024 + c) : (Wdt + row * 1024 + (c - 1024));
      dst = W_cat + i;
    } else {
      const long i = (v - T0 - T1) * 4;
      src = Wproj + i;
      dst = Wp + i;
    }
    const float4 f = *(const float4*)src;
    u16x4 o = {f2bf(f.x), f2bf(f.y), f2bf(f.z), f2bf(f.w)};
    *(u16x4*)dst = o;
  }
}

// ------ bf16 GEMM 128^2 (m97 schedule) + pair-row XOR LDS swizzle, fp32 out ----
// LDS layout: logical (row r, 16B-granule g) at physical row p=r>>1,
// slot (g+4*(r&1))^(p&7). Fragment ds_read_b128: each bank gets exactly
// 2 lanes (free). Staging via linear gload_lds with inverse-mapped source.
__global__ __launch_bounds__(256, 2)
void gemm_bt(const u16* __restrict__ A, const u16* __restrict__ B,
             float* __restrict__ C, const float* __restrict__ bias1,
             const float* __restrict__ bias2, int M, int N, int K) {
  __shared__ u16 As[128 * 32];
  __shared__ u16 Bs[128 * 32];
  const int t = threadIdx.x;
  const int w = t >> 6, l = t & 63;
  const int l15 = l & 15, lg = l >> 4;
  const int bm = blockIdx.x, bn = blockIdx.y;
  const int wr = (w >> 1) * 64, wc = (w & 1) * 64;
  const int wrh = (w >> 1) * 32, wch = (w & 1) * 32;
  f32x4 acc[4][4] = {};
  // staging geometry (swizzled): lane l, issue i -> phys row i*32+w*8+(l>>3),
  // slot l&7; logical r = i*64+w*16+rsub, granule sg
  const int su = (l & 7) ^ (l >> 3);
  const int rsub = 2 * (l >> 3) + (su >> 2);
  const int sg = su & 3;
  // fragment-read slot: logical row = base+l15, granule lg
  const int sfr = (lg + 4 * (l15 & 1)) ^ (l15 >> 1);
  const int lh = l15 >> 1;

  for (int kt = 0; kt < (K >> 5); ++kt) {
#pragma unroll
    for (int i = 0; i < 2; ++i) {
      const int r = i * 64 + w * 16 + rsub;
      gload_lds16(A + (long)(bm * 128 + r) * K + kt * 32 + sg * 8,
                  (char*)As + (i * 32 + w * 8) * 128);
      gload_lds16(B + (long)(bn * 128 + r) * K + kt * 32 + sg * 8,
                  (char*)Bs + (i * 32 + w * 8) * 128);
    }
    __syncthreads();
    short8 af[4], bfr[4];
#pragma unroll
    for (int m = 0; m < 4; ++m)
      af[m] = *(const short8*)&As[(wrh + m * 8 + lh) * 64 + sfr * 8];
#pragma unroll
    for (int n = 0; n < 4; ++n)
      bfr[n] = *(const short8*)&Bs[(wch + n * 8 + lh) * 64 + sfr * 8];
#pragma unroll
    for (int m = 0; m < 4; ++m)
#pragma unroll
      for (int n = 0; n < 4; ++n)
        acc[m][n] = __builtin_amdgcn_mfma_f32_16x16x32_bf16(af[m], bfr[n], acc[m][n], 0, 0, 0);
    __syncthreads();
  }
#pragma unroll
  for (int m = 0; m < 4; ++m) {
    const int row0 = bm * 128 + wr + m * 16 + lg * 4;
#pragma unroll
    for (int n = 0; n < 4; ++n) {
      const int col = bn * 128 + wc + n * 16 + l15;
      float bia = 0.f;
      if (bias1) bia += bias1[col];
      if (bias2) bia += bias2[col];
#pragma unroll
      for (int r = 0; r < 4; ++r)
        C[(long)(row0 + r) * N + col] = acc[m][n][r] + bia;
    }
  }
}

// ---------------- same structure + swizzle, bf16 out — QKV+dt GEMM ------------
__global__ __launch_bounds__(256, 2)
void gemm_bt_b16(const u16* __restrict__ A, const u16* __restrict__ B,
                 u16* __restrict__ C, const float* __restrict__ bias1,
                 const float* __restrict__ bias2, int M, int N, int K) {
  __shared__ u16 As[128 * 32];
  __shared__ u16 Bs[128 * 32];
  const int t = threadIdx.x;
  const int w = t >> 6, l = t & 63;
  const int l15 = l & 15, lg = l >> 4;
  const int bm = blockIdx.x, bn = blockIdx.y;
  const int wr = (w >> 1) * 64, wc = (w & 1) * 64;
  const int wrh = (w >> 1) * 32, wch = (w & 1) * 32;
  f32x4 acc[4][4] = {};
  const int su = (l & 7) ^ (l >> 3);
  const int rsub = 2 * (l >> 3) + (su >> 2);
  const int sg = su & 3;
  const int sfr = (lg + 4 * (l15 & 1)) ^ (l15 >> 1);
  const int lh = l15 >> 1;

  for (int kt = 0; kt < (K >> 5); ++kt) {
#pragma unroll
    for (int i = 0; i < 2; ++i) {
      const int r = i * 64 + w * 16 + rsub;
      gload_lds16(A + (long)(bm * 128 + r) * K + kt * 32 + sg * 8,
                  (char*)As + (i * 32 + w * 8) * 128);
      gload_lds16(B + (long)(bn * 128 + r) * K + kt * 32 + sg * 8,
                  (char*)Bs + (i * 32 + w * 8) * 128);
    }
    __syncthreads();
    short8 af[4], bfr[4];
#pragma unroll
    for (int m = 0; m < 4; ++m)
      af[m] = *(const short8*)&As[(wrh + m * 8 + lh) * 64 + sfr * 8];
#pragma unroll
    for (int n = 0; n < 4; ++n)
      bfr[n] = *(const short8*)&Bs[(wch + n * 8 + lh) * 64 + sfr * 8];
#pragma unroll
    for (int m = 0; m < 4; ++m)
#pragma unroll
      for (int n = 0; n < 4; ++n)
        acc[m][n] = __builtin_amdgcn_mfma_f32_16x16x32_bf16(af[m], bfr[n], acc[m][n], 0, 0, 0);
    __syncthreads();
  }
#pragma unroll
  for (int m = 0; m < 4; ++m) {
    const int row0 = bm * 128 + wr + m * 16 + lg * 4;
#pragma unroll
    for (int n = 0; n < 4; ++n) {
      const int col = bn * 128 + wc + n * 16 + l15;
      float bia = 0.f;
      if (bias1) bia += bias1[col];
      if (bias2) bia += bias2[col];
#pragma unroll
      for (int r = 0; r < 4; ++r)
        C[(long)(row0 + r) * N + col] = f2bf(acc[m][n][r] + bia);
    }
  }
}

// ---------------- fuse: split qkv (bf16), vres mix, LN(q,k), RoPE ----------------
__global__ __launch_bounds__(256)
void fuse_qkv2(const u16* __restrict__ qkv, const float* __restrict__ vres,
               const float* __restrict__ rope,
               const float* __restrict__ qg, const float* __restrict__ qb,
               const float* __restrict__ kg, const float* __restrict__ kb,
               const float* __restrict__ pl1, const float* __restrict__ pl2,
               u16* __restrict__ Q, u16* __restrict__ Ksw, u16* __restrict__ VTsw) {
  __shared__ u16 Vl[64][72];
  const int t = threadIdx.x, w = t >> 6, d = t & 63;
  const int bh = blockIdx.x, ntile = blockIdx.y;
  const int b = bh >> 4, h = bh & 15, n0 = ntile * 64;
  const float l1 = pl1[0], l2 = pl2[0];
  const float gq = qg[d], bq = qb[d];
  const float gk = kg[d], bk = kb[d];
  const float sgn = (d < 32) ? -1.f : 1.f;
  const int c = d >> 3, d7 = d & 7;

  for (int i = 0; i < 16; ++i) {
    const int nl = w * 16 + i;
    const int n = n0 + nl;
    const long base = ((long)(b * 1024 + n)) * 3072 + h * 64 + d;
    float q = bf2f(qkv[base]);
    float k = bf2f(qkv[base + 1024]);
    float v = bf2f(qkv[base + 2048]);
    v = l1 * v + l2 * vres[((long)(bh * 1024 + n)) * 64 + d];
    const float sinv = rope[n * 128 + d];
    const float cosv = rope[n * 128 + 64 + d];
    float s = q;
#pragma unroll
    for (int off = 1; off < 64; off <<= 1) s += __shfl_xor(s, off);
    const float qc = q - s * (1.f / 64.f);
    float vs = qc * qc;
#pragma unroll
    for (int off = 1; off < 64; off <<= 1) vs += __shfl_xor(vs, off);
    const float qn = qc * (1.f / sqrtf(vs * (1.f / 64.f) + 1e-5f)) * gq + bq;
    float s2 = k;
#pragma unroll
    for (int off = 1; off < 64; off <<= 1) s2 += __shfl_xor(s2, off);
    const float kc = k - s2 * (1.f / 64.f);
    float vs2 = kc * kc;
#pragma unroll
    for (int off = 1; off < 64; off <<= 1) vs2 += __shfl_xor(vs2, off);
    const float kn = kc * (1.f / sqrtf(vs2 * (1.f / 64.f) + 1e-5f)) * gk + bk;
    const float qo = __shfl_xor(qn, 32);
    const float ko = __shfl_xor(kn, 32);
    const float qr = qn * cosv + sgn * qo * sinv;
    const float kr = kn * cosv + sgn * ko * sinv;
    Q[(long)bh * 65536 + (long)n * 64 + d] = f2bf(qr);
    Ksw[(long)bh * 65536 + (long)n * 64 + ((c ^ (n & 7)) * 8 + d7)] = f2bf(kr);
    Vl[nl][d] = f2bf(v);
  }
  __syncthreads();
#pragma unroll
  for (int i = 0; i < 2; ++i) {
    const int task = i * 256 + t;
    const int dd = task >> 3, cc = task & 7;
    short8 o;
#pragma unroll
    for (int u = 0; u < 8; ++u) o[u] = (short)Vl[cc * 8 + u][dd];
    *(short8*)&VTsw[((long)(bh * 64 + dd)) * 1024 + n0 + ((cc ^ (dd & 7)) * 8)] = o;
  }
}

// -------- flash attention fwd v8: in-register P + KVBLK=128 (round-11) --------
__global__ __launch_bounds__(256, 4)
void attn_fwd8(const u16* __restrict__ Q, const u16* __restrict__ Ksw,
               const u16* __restrict__ VTsw, u16* __restrict__ Out) {
  __shared__ u16 Kl[128 * 64];
  __shared__ u16 Vl[64 * 128];
  const int t = threadIdx.x, w = t >> 6, l = t & 63;
  const int l15 = l & 15, lg = l >> 4;
  const int x7 = l15 & 7;
  const int bh = blockIdx.x, q0 = blockIdx.y * 64;
  const long bo = (long)bh * 65536;
  const bool hihalf = (l & 16) != 0;

  const int qrow = q0 + w * 16 + l15;
  short8 qf[2];
#pragma unroll
  for (int ks = 0; ks < 2; ++ks)
    qf[ks] = *(const short8*)&Q[bo + (long)qrow * 64 + ks * 32 + lg * 8];

  f32x4 acc[4] = {};
  float m_run = -1e30f, l_run = 0.f;

  for (int kb = 0; kb < 8; ++kb) {
    const int kvb = kb * 128;
#pragma unroll
    for (int i = 0; i < 4; ++i) {
      const int idx = i * 256 + t;
      const int krow = idx >> 3, kseg = idx & 7;
      gload_lds16(Ksw + bo + (long)(kvb + krow) * 64 + kseg * 8, (char*)Kl + idx * 16);
      const int vd = idx >> 4, vc = idx & 15;
      gload_lds16(VTsw + bo + (long)vd * 1024 + kvb + vc * 8,
                  (char*)Vl + vd * 256 + vc * 16);
    }
    __syncthreads();
#pragma unroll
    for (int tb = 0; tb < 2; ++tb) {
      f32x4 p[4];
#pragma unroll
      for (int mt = 0; mt < 4; ++mt) {
        f32x4 ps = {};
#pragma unroll
        for (int ks = 0; ks < 2; ++ks) {
          const short8 kf = *(const short8*)&Kl[(tb * 64 + mt * 16 + l15) * 64 +
                                                (((ks * 4 + lg) ^ x7) * 8)];
          ps = __builtin_amdgcn_mfma_f32_16x16x32_bf16(kf, qf[ks], ps, 0, 0, 0);
        }
        p[mt] = ps;
      }
      float mx = p[0][0];
#pragma unroll
      for (int mt = 0; mt < 4; ++mt)
#pragma unroll
        for (int r = 0; r < 4; ++r) mx = fmaxf(mx, p[mt][r]);
      mx = fmaxf(mx, __shfl_xor(mx, 16));
      mx = fmaxf(mx, __shfl_xor(mx, 32));
      const float mnew = fmaxf(m_run, mx * 0.125f);
      const float alpha = __expf(m_run - mnew);
      m_run = mnew;
      float sum = 0.f;
#pragma unroll
      for (int mt = 0; mt < 4; ++mt)
#pragma unroll
        for (int r = 0; r < 4; ++r) {
          const float e = __expf(p[mt][r] * 0.125f - mnew);
          p[mt][r] = e;
          sum += e;
        }
      sum += __shfl_xor(sum, 16);
      sum += __shfl_xor(sum, 32);
      l_run = l_run * alpha + sum;
      uint32_t u0[4], u1[4];
#pragma unroll
      for (int mt = 0; mt < 4; ++mt) {
        u0[mt] = cvt_pk_bf16(p[mt][0], p[mt][1]);
        u1[mt] = cvt_pk_bf16(p[mt][2], p[mt][3]);
      }
#pragma unroll
      for (int mt = 0; mt < 4; ++mt)
#pragma unroll
        for (int r = 0; r < 4; ++r) acc[mt][r] *= alpha;
#pragma unroll
      for (int ks = 0; ks < 2; ++ks) {
        uint32_t X0 = u0[2 * ks], Y0 = u0[2 * ks + 1];
        asm("v_permlane32_swap_b32 %0, %1" : "+v"(X0), "+v"(Y0));
        uint32_t X1 = u1[2 * ks], Y1 = u1[2 * ks + 1];
        asm("v_permlane32_swap_b32 %0, %1" : "+v"(X1), "+v"(Y1));
        const uint32_t Xs0 = (uint32_t)__shfl_xor((int)X0, 16);
        const uint32_t Ys0 = (uint32_t)__shfl_xor((int)Y0, 16);
        const uint32_t Xs1 = (uint32_t)__shfl_xor((int)X1, 16);
        const uint32_t Ys1 = (uint32_t)__shfl_xor((int)Y1, 16);
        u32x4 pv;
        pv[0] = hihalf ? Ys0 : X0;
        pv[1] = hihalf ? Ys1 : X1;
        pv[2] = hihalf ? Y0 : Xs0;
        pv[3] = hihalf ? Y1 : Xs1;
        const short8 pf = __builtin_bit_cast(short8, pv);
#pragma unroll
        for (int mt = 0; mt < 4; ++mt) {
          const short8 vf = *(const short8*)&Vl[(mt * 16 + l15) * 128 + tb * 64 +
                                                (((ks * 4 + lg) ^ x7) * 8)];
          acc[mt] = __builtin_amdgcn_mfma_f32_16x16x32_bf16(vf, pf, acc[mt], 0, 0, 0);
        }
      }
    }
    __syncthreads();
  }
  const int b = bh >> 4, h = bh & 15;
  const float inv = 1.f / l_run;
  const long obase = ((long)(b * 1024 + qrow)) * 1024 + h * 64;
#pragma unroll
  for (int mt = 0; mt < 4; ++mt) {
    const long o = obase + mt * 16 + lg * 4;
    *(uint32_t*)&Out[o] =
        (uint32_t)f2bf(acc[mt][0] * inv) | ((uint32_t)f2bf(acc[mt][1] * inv) << 16);
    *(uint32_t*)&Out[o + 2] =
        (uint32_t)f2bf(acc[mt][2] * inv) | ((uint32_t)f2bf(acc[mt][3] * inv) << 16);
  }
}

extern "C" void kernel_launch(void* const* d_in, const int* in_sizes, int n_in,
                              void* d_out, int out_size, void* d_ws, size_t ws_size,
                              hipStream_t stream) {
  const float* x     = (const float*)d_in[0];
  const float* rope  = (const float*)d_in[1];
  const float* dte   = (const float*)d_in[2];
  const float* vres  = (const float*)d_in[3];
  const float* Wqkv  = (const float*)d_in[4];
  const float* bqkv  = (const float*)d_in[5];
  const float* Wdt   = (const float*)d_in[6];
  const float* bdt   = (const float*)d_in[7];
  const float* qn_g  = (const float*)d_in[8];
  const float* qn_b  = (const float*)d_in[9];
  const float* kn_g  = (const float*)d_in[10];
  const float* kn_b  = (const float*)d_in[11];
  const float* l1    = (const float*)d_in[12];
  const float* l2    = (const float*)d_in[13];
  const float* Wproj = (const float*)d_in[14];
  const float* bproj = (const float*)d_in[15];
  float* out = (float*)d_out;

  char* ws = (char*)d_ws;
  u16*   A_cat = (u16*)(ws);                    // [4096,2048] bf16
  u16*   W_cat = (u16*)(ws + 16777216);         // [3072,2048] bf16
  u16*   Wp    = (u16*)(ws + 29360128);         // [1024,1024] bf16
  u16*   qkvb  = (u16*)(ws + 31457280);         // [4096,3072] bf16
  u16*   Qb    = (u16*)(ws + 56623104);         // [64,1024,64] bf16
  u16*   Ksw   = (u16*)(ws + 65011712);         // swizzled K
  u16*   VTsw  = (u16*)(ws + 73400320);         // swizzled V^T
  u16*   AO    = (u16*)(ws + 81788928);         // [4096,1024] bf16
  // total ws usage: 90,177,536 bytes

  cvt_all<<<2048, 256, 0, stream>>>(x, dte, Wqkv, Wdt, Wproj, A_cat, W_cat, Wp);
  gemm_bt_b16<<<dim3(32, 24), 256, 0, stream>>>(A_cat, W_cat, qkvb, bqkv, bdt,
                                                4096, 3072, 2048);
  fuse_qkv2<<<dim3(64, 16), 256, 0, stream>>>(qkvb, vres, rope, qn_g, qn_b, kn_g, kn_b,
                                              l1, l2, Qb, Ksw, VTsw);
  attn_fwd8<<<dim3(64, 16), 256, 0, stream>>>(Qb, Ksw, VTsw, AO);
  gemm_bt<<<dim3(32, 8), 256, 0, stream>>>(AO, Wp, out, bproj, nullptr, 4096, 1024, 1024);
}

// Round 14
// 161.393 us; speedup vs baseline: 1.0724x; 1.0271x over previous
//
#include <hip/hip_runtime.h>
#include <stdint.h>

typedef unsigned short u16;
typedef __attribute__((ext_vector_type(8))) short short8;
typedef __attribute__((ext_vector_type(4))) float f32x4;
typedef __attribute__((ext_vector_type(4))) unsigned short u16x4;
typedef __attribute__((ext_vector_type(4))) unsigned int u32x4;

#define DEVI __device__ __forceinline__

DEVI u16 f2bf(float f) {
  uint32_t u = __builtin_bit_cast(uint32_t, f);
  u += 0x7fffu + ((u >> 16) & 1u);
  return (u16)(u >> 16);
}

DEVI float bf2f(u16 u) {
  uint32_t v = ((uint32_t)u) << 16;
  return __builtin_bit_cast(float, v);
}

DEVI uint32_t cvt_pk_bf16(float lo, float hi) {
  uint32_t r;
  asm("v_cvt_pk_bf16_f32 %0, %1, %2" : "=v"(r) : "v"(lo), "v"(hi));
  return r;
}

DEVI void gload_lds16(const void* g, void* l) {
  __builtin_amdgcn_global_load_lds(
      (const __attribute__((address_space(1))) void*)g,
      (__attribute__((address_space(3))) void*)(uint32_t)(uintptr_t)l,
      16, 0, 0);
}

// ---------------- merged convert: A_cat, W_cat, Wp in one sweep ----------------
__global__ void cvt_all(const float* __restrict__ x, const float* __restrict__ dte,
                        const float* __restrict__ Wqkv, const float* __restrict__ Wdt,
                        const float* __restrict__ Wproj,
                        u16* __restrict__ A_cat, u16* __restrict__ W_cat,
                        u16* __restrict__ Wp) {
  const long T0 = (long)4096 * 2048 / 4;
  const long T1 = (long)3072 * 2048 / 4;
  const long T2 = (long)1024 * 1024 / 4;
  for (long v = (long)blockIdx.x * 256 + threadIdx.x; v < T0 + T1 + T2;
       v += (long)gridDim.x * 256) {
    const float* src;
    u16* dst;
    if (v < T0) {
      const long i = v * 4;
      const long row = i >> 11, c = i & 2047;
      src = (c < 1024) ? (x + row * 1024 + c) : (dte + row * 1024 + (c - 1024));
      dst = A_cat + i;
    } else if (v < T0 + T1) {
      const long i = (v - T0) * 4;
      const long row = i >> 11, c = i & 2047;
      src = (c < 1024) ? (Wqkv + row * 1024 + c) : (Wdt + row * 1024 + (c - 1024));
      dst = W_cat + i;
    } else {
      const long i = (v - T0 - T1) * 4;
      src = Wproj + i;
      dst = Wp + i;
    }
    const float4 f = *(const float4*)src;
    u16x4 o = {f2bf(f.x), f2bf(f.y), f2bf(f.z), f2bf(f.w)};
    *(u16x4*)dst = o;
  }
}

// ------ bf16 GEMM 64x128 tile (m97 schedule + pair-row swizzle), fp32 out ------
// For proj: M/64 x N/128 grid = 512 blocks = 2 blocks/CU (vs 1 with 128^2).
// Same pair-row XOR LDS layout as validated round-12 swizzle.
__global__ __launch_bounds__(256, 2)
void gemm_bt64(const u16* __restrict__ A, const u16* __restrict__ B,
               float* __restrict__ C, const float* __restrict__ bias1,
               int M, int N, int K) {
  __shared__ u16 As[64 * 32];    // 32 phys rows x 64 u16
  __shared__ u16 Bs[128 * 32];   // 64 phys rows x 64 u16
  const int t = threadIdx.x;
  const int w = t >> 6, l = t & 63;
  const int l15 = l & 15, lg = l >> 4;
  const int bm = blockIdx.x, bn = blockIdx.y;
  const int wr = (w >> 1) * 32, wc = (w & 1) * 64;  // wave quadrant 32x64
  f32x4 acc[2][4] = {};
  // staging swizzle geometry (round-12 validated algebra)
  const int su = (l & 7) ^ (l >> 3);
  const int rsub = 2 * (l >> 3) + (su >> 2);
  const int sg = su & 3;
  const int sfr = (lg + 4 * (l15 & 1)) ^ (l15 >> 1);
  const int lh = l15 >> 1;

  for (int kt = 0; kt < (K >> 5); ++kt) {
    {  // As: 64 rows, 256 chunks, 1 per thread (all 4 waves)
      const int r = w * 16 + rsub;
      gload_lds16(A + (long)(bm * 64 + r) * K + kt * 32 + sg * 8,
                  (char*)As + (w * 8) * 128);
    }
#pragma unroll
    for (int i = 0; i < 2; ++i) {  // Bs: 128 rows, 512 chunks, 2 per thread
      const int r = i * 64 + w * 16 + rsub;
      gload_lds16(B + (long)(bn * 128 + r) * K + kt * 32 + sg * 8,
                  (char*)Bs + (i * 32 + w * 8) * 128);
    }
    __syncthreads();
    short8 af[2], bfr[4];
#pragma unroll
    for (int m = 0; m < 2; ++m)
      af[m] = *(const short8*)&As[((w >> 1) * 16 + m * 8 + lh) * 64 + sfr * 8];
#pragma unroll
    for (int n = 0; n < 4; ++n)
      bfr[n] = *(const short8*)&Bs[((w & 1) * 32 + n * 8 + lh) * 64 + sfr * 8];
#pragma unroll
    for (int m = 0; m < 2; ++m)
#pragma unroll
      for (int n = 0; n < 4; ++n)
        acc[m][n] = __builtin_amdgcn_mfma_f32_16x16x32_bf16(af[m], bfr[n], acc[m][n], 0, 0, 0);
    __syncthreads();
  }
#pragma unroll
  for (int m = 0; m < 2; ++m) {
    const int row0 = bm * 64 + wr + m * 16 + lg * 4;
#pragma unroll
    for (int n = 0; n < 4; ++n) {
      const int col = bn * 128 + wc + n * 16 + l15;
      const float bia = bias1 ? bias1[col] : 0.f;
#pragma unroll
      for (int r = 0; r < 4; ++r)
        C[(long)(row0 + r) * N + col] = acc[m][n][r] + bia;
    }
  }
}

// ------ bf16 GEMM 128^2 (m97 schedule + swizzle), bf16 out — QKV+dt GEMM ------
__global__ __launch_bounds__(256, 2)
void gemm_bt_b16(const u16* __restrict__ A, const u16* __restrict__ B,
                 u16* __restrict__ C, const float* __restrict__ bias1,
                 const float* __restrict__ bias2, int M, int N, int K) {
  __shared__ u16 As[128 * 32];
  __shared__ u16 Bs[128 * 32];
  const int t = threadIdx.x;
  const int w = t >> 6, l = t & 63;
  const int l15 = l & 15, lg = l >> 4;
  const int bm = blockIdx.x, bn = blockIdx.y;
  const int wr = (w >> 1) * 64, wc = (w & 1) * 64;
  const int wrh = (w >> 1) * 32, wch = (w & 1) * 32;
  f32x4 acc[4][4] = {};
  const int su = (l & 7) ^ (l >> 3);
  const int rsub = 2 * (l >> 3) + (su >> 2);
  const int sg = su & 3;
  const int sfr = (lg + 4 * (l15 & 1)) ^ (l15 >> 1);
  const int lh = l15 >> 1;

  for (int kt = 0; kt < (K >> 5); ++kt) {
#pragma unroll
    for (int i = 0; i < 2; ++i) {
      const int r = i * 64 + w * 16 + rsub;
      gload_lds16(A + (long)(bm * 128 + r) * K + kt * 32 + sg * 8,
                  (char*)As + (i * 32 + w * 8) * 128);
      gload_lds16(B + (long)(bn * 128 + r) * K + kt * 32 + sg * 8,
                  (char*)Bs + (i * 32 + w * 8) * 128);
    }
    __syncthreads();
    short8 af[4], bfr[4];
#pragma unroll
    for (int m = 0; m < 4; ++m)
      af[m] = *(const short8*)&As[(wrh + m * 8 + lh) * 64 + sfr * 8];
#pragma unroll
    for (int n = 0; n < 4; ++n)
      bfr[n] = *(const short8*)&Bs[(wch + n * 8 + lh) * 64 + sfr * 8];
#pragma unroll
    for (int m = 0; m < 4; ++m)
#pragma unroll
      for (int n = 0; n < 4; ++n)
        acc[m][n] = __builtin_amdgcn_mfma_f32_16x16x32_bf16(af[m], bfr[n], acc[m][n], 0, 0, 0);
    __syncthreads();
  }
#pragma unroll
  for (int m = 0; m < 4; ++m) {
    const int row0 = bm * 128 + wr + m * 16 + lg * 4;
#pragma unroll
    for (int n = 0; n < 4; ++n) {
      const int col = bn * 128 + wc + n * 16 + l15;
      float bia = 0.f;
      if (bias1) bia += bias1[col];
      if (bias2) bia += bias2[col];
#pragma unroll
      for (int r = 0; r < 4; ++r)
        C[(long)(row0 + r) * N + col] = f2bf(acc[m][n][r] + bia);
    }
  }
}

// ---------------- fuse: split qkv (bf16), vres mix, LN(q,k), RoPE ----------------
__global__ __launch_bounds__(256)
void fuse_qkv2(const u16* __restrict__ qkv, const float* __restrict__ vres,
               const float* __restrict__ rope,
               const float* __restrict__ qg, const float* __restrict__ qb,
               const float* __restrict__ kg, const float* __restrict__ kb,
               const float* __restrict__ pl1, const float* __restrict__ pl2,
               u16* __restrict__ Q, u16* __restrict__ Ksw, u16* __restrict__ VTsw) {
  __shared__ u16 Vl[64][72];
  const int t = threadIdx.x, w = t >> 6, d = t & 63;
  const int bh = blockIdx.x, ntile = blockIdx.y;
  const int b = bh >> 4, h = bh & 15, n0 = ntile * 64;
  const float l1 = pl1[0], l2 = pl2[0];
  const float gq = qg[d], bq = qb[d];
  const float gk = kg[d], bk = kb[d];
  const float sgn = (d < 32) ? -1.f : 1.f;
  const int c = d >> 3, d7 = d & 7;

  for (int i = 0; i < 16; ++i) {
    const int nl = w * 16 + i;
    const int n = n0 + nl;
    const long base = ((long)(b * 1024 + n)) * 3072 + h * 64 + d;
    float q = bf2f(qkv[base]);
    float k = bf2f(qkv[base + 1024]);
    float v = bf2f(qkv[base + 2048]);
    v = l1 * v + l2 * vres[((long)(bh * 1024 + n)) * 64 + d];
    const float sinv = rope[n * 128 + d];
    const float cosv = rope[n * 128 + 64 + d];
    float s = q;
#pragma unroll
    for (int off = 1; off < 64; off <<= 1) s += __shfl_xor(s, off);
    const float qc = q - s * (1.f / 64.f);
    float vs = qc * qc;
#pragma unroll
    for (int off = 1; off < 64; off <<= 1) vs += __shfl_xor(vs, off);
    const float qn = qc * (1.f / sqrtf(vs * (1.f / 64.f) + 1e-5f)) * gq + bq;
    float s2 = k;
#pragma unroll
    for (int off = 1; off < 64; off <<= 1) s2 += __shfl_xor(s2, off);
    const float kc = k - s2 * (1.f / 64.f);
    float vs2 = kc * kc;
#pragma unroll
    for (int off = 1; off < 64; off <<= 1) vs2 += __shfl_xor(vs2, off);
    const float kn = kc * (1.f / sqrtf(vs2 * (1.f / 64.f) + 1e-5f)) * gk + bk;
    const float qo = __shfl_xor(qn, 32);
    const float ko = __shfl_xor(kn, 32);
    const float qr = qn * cosv + sgn * qo * sinv;
    const float kr = kn * cosv + sgn * ko * sinv;
    Q[(long)bh * 65536 + (long)n * 64 + d] = f2bf(qr);
    Ksw[(long)bh * 65536 + (long)n * 64 + ((c ^ (n & 7)) * 8 + d7)] = f2bf(kr);
    Vl[nl][d] = f2bf(v);
  }
  __syncthreads();
#pragma unroll
  for (int i = 0; i < 2; ++i) {
    const int task = i * 256 + t;
    const int dd = task >> 3, cc = task & 7;
    short8 o;
#pragma unroll
    for (int u = 0; u < 8; ++u) o[u] = (short)Vl[cc * 8 + u][dd];
    *(short8*)&VTsw[((long)(bh * 64 + dd)) * 1024 + n0 + ((cc ^ (dd & 7)) * 8)] = o;
  }
}

// -------- flash attention fwd v8: in-register P + KVBLK=128 (round-11) --------
__global__ __launch_bounds__(256, 4)
void attn_fwd8(const u16* __restrict__ Q, const u16* __restrict__ Ksw,
               const u16* __restrict__ VTsw, u16* __restrict__ Out) {
  __shared__ u16 Kl[128 * 64];
  __shared__ u16 Vl[64 * 128];
  const int t = threadIdx.x, w = t >> 6, l = t & 63;
  const int l15 = l & 15, lg = l >> 4;
  const int x7 = l15 & 7;
  const int bh = blockIdx.x, q0 = blockIdx.y * 64;
  const long bo = (long)bh * 65536;
  const bool hihalf = (l & 16) != 0;

  const int qrow = q0 + w * 16 + l15;
  short8 qf[2];
#pragma unroll
  for (int ks = 0; ks < 2; ++ks)
    qf[ks] = *(const short8*)&Q[bo + (long)qrow * 64 + ks * 32 + lg * 8];

  f32x4 acc[4] = {};
  float m_run = -1e30f, l_run = 0.f;

  for (int kb = 0; kb < 8; ++kb) {
    const int kvb = kb * 128;
#pragma unroll
    for (int i = 0; i < 4; ++i) {
      const int idx = i * 256 + t;
      const int krow = idx >> 3, kseg = idx & 7;
      gload_lds16(Ksw + bo + (long)(kvb + krow) * 64 + kseg * 8, (char*)Kl + idx * 16);
      const int vd = idx >> 4, vc = idx & 15;
      gload_lds16(VTsw + bo + (long)vd * 1024 + kvb + vc * 8,
                  (char*)Vl + vd * 256 + vc * 16);
    }
    __syncthreads();
#pragma unroll
    for (int tb = 0; tb < 2; ++tb) {
      f32x4 p[4];
#pragma unroll
      for (int mt = 0; mt < 4; ++mt) {
        f32x4 ps = {};
#pragma unroll
        for (int ks = 0; ks < 2; ++ks) {
          const short8 kf = *(const short8*)&Kl[(tb * 64 + mt * 16 + l15) * 64 +
                                                (((ks * 4 + lg) ^ x7) * 8)];
          ps = __builtin_amdgcn_mfma_f32_16x16x32_bf16(kf, qf[ks], ps, 0, 0, 0);
        }
        p[mt] = ps;
      }
      float mx = p[0][0];
#pragma unroll
      for (int mt = 0; mt < 4; ++mt)
#pragma unroll
        for (int r = 0; r < 4; ++r) mx = fmaxf(mx, p[mt][r]);
      mx = fmaxf(mx, __shfl_xor(mx, 16));
      mx = fmaxf(mx, __shfl_xor(mx, 32));
      const float mnew = fmaxf(m_run, mx * 0.125f);
      const float alpha = __expf(m_run - mnew);
      m_run = mnew;
      float sum = 0.f;
#pragma unroll
      for (int mt = 0; mt < 4; ++mt)
#pragma unroll
        for (int r = 0; r < 4; ++r) {
          const float e = __expf(p[mt][r] * 0.125f - mnew);
          p[mt][r] = e;
          sum += e;
        }
      sum += __shfl_xor(sum, 16);
      sum += __shfl_xor(sum, 32);
      l_run = l_run * alpha + sum;
      uint32_t u0[4], u1[4];
#pragma unroll
      for (int mt = 0; mt < 4; ++mt) {
        u0[mt] = cvt_pk_bf16(p[mt][0], p[mt][1]);
        u1[mt] = cvt_pk_bf16(p[mt][2], p[mt][3]);
      }
#pragma unroll
      for (int mt = 0; mt < 4; ++mt)
#pragma unroll
        for (int r = 0; r < 4; ++r) acc[mt][r] *= alpha;
#pragma unroll
      for (int ks = 0; ks < 2; ++ks) {
        uint32_t X0 = u0[2 * ks], Y0 = u0[2 * ks + 1];
        asm("v_permlane32_swap_b32 %0, %1" : "+v"(X0), "+v"(Y0));
        uint32_t X1 = u1[2 * ks], Y1 = u1[2 * ks + 1];
        asm("v_permlane32_swap_b32 %0, %1" : "+v"(X1), "+v"(Y1));
        const uint32_t Xs0 = (uint32_t)__shfl_xor((int)X0, 16);
        const uint32_t Ys0 = (uint32_t)__shfl_xor((int)Y0, 16);
        const uint32_t Xs1 = (uint32_t)__shfl_xor((int)X1, 16);
        const uint32_t Ys1 = (uint32_t)__shfl_xor((int)Y1, 16);
        u32x4 pv;
        pv[0] = hihalf ? Ys0 : X0;
        pv[1] = hihalf ? Ys1 : X1;
        pv[2] = hihalf ? Y0 : Xs0;
        pv[3] = hihalf ? Y1 : Xs1;
        const short8 pf = __builtin_bit_cast(short8, pv);
#pragma unroll
        for (int mt = 0; mt < 4; ++mt) {
          const short8 vf = *(const short8*)&Vl[(mt * 16 + l15) * 128 + tb * 64 +
                                                (((ks * 4 + lg) ^ x7) * 8)];
          acc[mt] = __builtin_amdgcn_mfma_f32_16x16x32_bf16(vf, pf, acc[mt], 0, 0, 0);
        }
      }
    }
    __syncthreads();
  }
  const int b = bh >> 4, h = bh & 15;
  const float inv = 1.f / l_run;
  const long obase = ((long)(b * 1024 + qrow)) * 1024 + h * 64;
#pragma unroll
  for (int mt = 0; mt < 4; ++mt) {
    const long o = obase + mt * 16 + lg * 4;
    *(uint32_t*)&Out[o] = cvt_pk_bf16(acc[mt][0] * inv, acc[mt][1] * inv);
    *(uint32_t*)&Out[o + 2] = cvt_pk_bf16(acc[mt][2] * inv, acc[mt][3] * inv);
  }
}

extern "C" void kernel_launch(void* const* d_in, const int* in_sizes, int n_in,
                              void* d_out, int out_size, void* d_ws, size_t ws_size,
                              hipStream_t stream) {
  const float* x     = (const float*)d_in[0];
  const float* rope  = (const float*)d_in[1];
  const float* dte   = (const float*)d_in[2];
  const float* vres  = (const float*)d_in[3];
  const float* Wqkv  = (const float*)d_in[4];
  const float* bqkv  = (const float*)d_in[5];
  const float* Wdt   = (const float*)d_in[6];
  const float* bdt   = (const float*)d_in[7];
  const float* qn_g  = (const float*)d_in[8];
  const float* qn_b  = (const float*)d_in[9];
  const float* kn_g  = (const float*)d_in[10];
  const float* kn_b  = (const float*)d_in[11];
  const float* l1    = (const float*)d_in[12];
  const float* l2    = (const float*)d_in[13];
  const float* Wproj = (const float*)d_in[14];
  const float* bproj = (const float*)d_in[15];
  float* out = (float*)d_out;

  char* ws = (char*)d_ws;
  u16*   A_cat = (u16*)(ws);                    // [4096,2048] bf16
  u16*   W_cat = (u16*)(ws + 16777216);         // [3072,2048] bf16
  u16*   Wp    = (u16*)(ws + 29360128);         // [1024,1024] bf16
  u16*   qkvb  = (u16*)(ws + 31457280);         // [4096,3072] bf16
  u16*   Qb    = (u16*)(ws + 56623104);         // [64,1024,64] bf16
  u16*   Ksw   = (u16*)(ws + 65011712);         // swizzled K
  u16*   VTsw  = (u16*)(ws + 73400320);         // swizzled V^T
  u16*   AO    = (u16*)(ws + 81788928);         // [4096,1024] bf16
  // total ws usage: 90,177,536 bytes

  cvt_all<<<2048, 256, 0, stream>>>(x, dte, Wqkv, Wdt, Wproj, A_cat, W_cat, Wp);
  gemm_bt_b16<<<dim3(32, 24), 256, 0, stream>>>(A_cat, W_cat, qkvb, bqkv, bdt,
                                                4096, 3072, 2048);
  fuse_qkv2<<<dim3(64, 16), 256, 0, stream>>>(qkvb, vres, rope, qn_g, qn_b, kn_g, kn_b,
                                              l1, l2, Qb, Ksw, VTsw);
  attn_fwd8<<<dim3(64, 16), 256, 0, stream>>>(Qb, Ksw, VTsw, AO);
  // proj GEMM: 64x128 tile -> 512 blocks = 2 blocks/CU
  gemm_bt64<<<dim3(64, 8), 256, 0, stream>>>(AO, Wp, out, bproj, 4096, 1024, 1024);
}

// Round 15
// 146.674 us; speedup vs baseline: 1.1800x; 1.1004x over previous
//
#include <hip/hip_runtime.h>
#include <stdint.h>

typedef unsigned short u16;
typedef __attribute__((ext_vector_type(8))) short short8;
typedef __attribute__((ext_vector_type(4))) float f32x4;
typedef __attribute__((ext_vector_type(4))) unsigned short u16x4;
typedef __attribute__((ext_vector_type(4))) unsigned int u32x4;

#define DEVI __device__ __forceinline__

DEVI u16 f2bf(float f) {
  uint32_t u = __builtin_bit_cast(uint32_t, f);
  u += 0x7fffu + ((u >> 16) & 1u);
  return (u16)(u >> 16);
}

DEVI float bf2f(u16 u) {
  uint32_t v = ((uint32_t)u) << 16;
  return __builtin_bit_cast(float, v);
}

DEVI uint32_t cvt_pk_bf16(float lo, float hi) {
  uint32_t r;
  asm("v_cvt_pk_bf16_f32 %0, %1, %2" : "=v"(r) : "v"(lo), "v"(hi));
  return r;
}

DEVI void gload_lds16(const void* g, void* l) {
  __builtin_amdgcn_global_load_lds(
      (const __attribute__((address_space(1))) void*)g,
      (__attribute__((address_space(3))) void*)(uint32_t)(uintptr_t)l,
      16, 0, 0);
}

// ---------------- merged convert: A_cat, W_cat, Wp in one sweep ----------------
__global__ void cvt_all(const float* __restrict__ x, const float* __restrict__ dte,
                        const float* __restrict__ Wqkv, const float* __restrict__ Wdt,
                        const float* __restrict__ Wproj,
                        u16* __restrict__ A_cat, u16* __restrict__ W_cat,
                        u16* __restrict__ Wp) {
  const long T0 = (long)4096 * 2048 / 4;
  const long T1 = (long)3072 * 2048 / 4;
  const long T2 = (long)1024 * 1024 / 4;
  for (long v = (long)blockIdx.x * 256 + threadIdx.x; v < T0 + T1 + T2;
       v += (long)gridDim.x * 256) {
    const float* src;
    u16* dst;
    if (v < T0) {
      const long i = v * 4;
      const long row = i >> 11, c = i & 2047;
      src = (c < 1024) ? (x + row * 1024 + c) : (dte + row * 1024 + (c - 1024));
      dst = A_cat + i;
    } else if (v < T0 + T1) {
      const long i = (v - T0) * 4;
      const long row = i >> 11, c = i & 2047;
      src = (c < 1024) ? (Wqkv + row * 1024 + c) : (Wdt + row * 1024 + (c - 1024));
      dst = W_cat + i;
    } else {
      const long i = (v - T0 - T1) * 4;
      src = Wproj + i;
      dst = Wp + i;
    }
    const float4 f = *(const float4*)src;
    u16x4 o = {f2bf(f.x), f2bf(f.y), f2bf(f.z), f2bf(f.w)};
    *(u16x4*)dst = o;
  }
}

// ------ bf16 GEMM 64x128 tile (m97 schedule + pair-row swizzle), fp32 out ------
__global__ __launch_bounds__(256, 2)
void gemm_bt64(const u16* __restrict__ A, const u16* __restrict__ B,
               float* __restrict__ C, const float* __restrict__ bias1,
               int M, int N, int K) {
  __shared__ u16 As[64 * 32];
  __shared__ u16 Bs[128 * 32];
  const int t = threadIdx.x;
  const int w = t >> 6, l = t & 63;
  const int l15 = l & 15, lg = l >> 4;
  const int bm = blockIdx.x, bn = blockIdx.y;
  const int wr = (w >> 1) * 32, wc = (w & 1) * 64;
  f32x4 acc[2][4] = {};
  const int su = (l & 7) ^ (l >> 3);
  const int rsub = 2 * (l >> 3) + (su >> 2);
  const int sg = su & 3;
  const int sfr = (lg + 4 * (l15 & 1)) ^ (l15 >> 1);
  const int lh = l15 >> 1;

  for (int kt = 0; kt < (K >> 5); ++kt) {
    {
      const int r = w * 16 + rsub;
      gload_lds16(A + (long)(bm * 64 + r) * K + kt * 32 + sg * 8,
                  (char*)As + (w * 8) * 128);
    }
#pragma unroll
    for (int i = 0; i < 2; ++i) {
      const int r = i * 64 + w * 16 + rsub;
      gload_lds16(B + (long)(bn * 128 + r) * K + kt * 32 + sg * 8,
                  (char*)Bs + (i * 32 + w * 8) * 128);
    }
    __syncthreads();
    short8 af[2], bfr[4];
#pragma unroll
    for (int m = 0; m < 2; ++m)
      af[m] = *(const short8*)&As[((w >> 1) * 16 + m * 8 + lh) * 64 + sfr * 8];
#pragma unroll
    for (int n = 0; n < 4; ++n)
      bfr[n] = *(const short8*)&Bs[((w & 1) * 32 + n * 8 + lh) * 64 + sfr * 8];
#pragma unroll
    for (int m = 0; m < 2; ++m)
#pragma unroll
      for (int n = 0; n < 4; ++n)
        acc[m][n] = __builtin_amdgcn_mfma_f32_16x16x32_bf16(af[m], bfr[n], acc[m][n], 0, 0, 0);
    __syncthreads();
  }
#pragma unroll
  for (int m = 0; m < 2; ++m) {
    const int row0 = bm * 64 + wr + m * 16 + lg * 4;
#pragma unroll
    for (int n = 0; n < 4; ++n) {
      const int col = bn * 128 + wc + n * 16 + l15;
      const float bia = bias1 ? bias1[col] : 0.f;
#pragma unroll
      for (int r = 0; r < 4; ++r)
        C[(long)(row0 + r) * N + col] = acc[m][n][r] + bia;
    }
  }
}

// ------ fused QKV GEMM: 128^2 m97+swizzle, epilogue does LN/RoPE/v-mix --------
// Block bn<8: Q (LN+RoPE -> Q row-major). bn<16: K (LN+RoPE -> Ksw chunk-swz).
// bn>=16: V (l1*v + l2*vres -> LDS transpose -> VTsw chunk-swz).
// Wave quadrant = 64 tokens x 64 cols = exactly one head (d = n*16+l15).
__global__ __launch_bounds__(256, 2)
void gemm_qkv_fused(const u16* __restrict__ A, const u16* __restrict__ B,
                    const float* __restrict__ bqkv, const float* __restrict__ bdt,
                    const float* __restrict__ vres, const float* __restrict__ rope,
                    const float* __restrict__ qg, const float* __restrict__ qb,
                    const float* __restrict__ kg, const float* __restrict__ kb,
                    const float* __restrict__ pl1, const float* __restrict__ pl2,
                    u16* __restrict__ Q, u16* __restrict__ Ksw,
                    u16* __restrict__ VTsw, int M, int N, int K) {
  __shared__ u16 As[128 * 32];
  __shared__ u16 Bs[128 * 32];
  __shared__ u16 vsc[2][64][66];  // V-transpose scratch, pitch 66 (bank spread)
  const int t = threadIdx.x;
  const int w = t >> 6, l = t & 63;
  const int l15 = l & 15, lg = l >> 4;
  const int bm = blockIdx.x, bn = blockIdx.y;
  const int wr = (w >> 1) * 64, wc = (w & 1) * 64;
  const int wrh = (w >> 1) * 32, wch = (w & 1) * 32;
  f32x4 acc[4][4] = {};
  const int su = (l & 7) ^ (l >> 3);
  const int rsub = 2 * (l >> 3) + (su >> 2);
  const int sg = su & 3;
  const int sfr = (lg + 4 * (l15 & 1)) ^ (l15 >> 1);
  const int lh = l15 >> 1;

  for (int kt = 0; kt < (K >> 5); ++kt) {
#pragma unroll
    for (int i = 0; i < 2; ++i) {
      const int r = i * 64 + w * 16 + rsub;
      gload_lds16(A + (long)(bm * 128 + r) * K + kt * 32 + sg * 8,
                  (char*)As + (i * 32 + w * 8) * 128);
      gload_lds16(B + (long)(bn * 128 + r) * K + kt * 32 + sg * 8,
                  (char*)Bs + (i * 32 + w * 8) * 128);
    }
    __syncthreads();
    short8 af[4], bfr[4];
#pragma unroll
    for (int m = 0; m < 4; ++m)
      af[m] = *(const short8*)&As[(wrh + m * 8 + lh) * 64 + sfr * 8];
#pragma unroll
    for (int n = 0; n < 4; ++n)
      bfr[n] = *(const short8*)&Bs[(wch + n * 8 + lh) * 64 + sfr * 8];
#pragma unroll
    for (int m = 0; m < 4; ++m)
#pragma unroll
      for (int n = 0; n < 4; ++n)
        acc[m][n] = __builtin_amdgcn_mfma_f32_16x16x32_bf16(af[m], bfr[n], acc[m][n], 0, 0, 0);
    __syncthreads();
  }

  // ---- fused epilogue ----
  float biasv[4];
#pragma unroll
  for (int n = 0; n < 4; ++n) {
    const int col = bn * 128 + wc + n * 16 + l15;
    biasv[n] = bqkv[col] + bdt[col];
  }
  const int h = (bn & 7) * 2 + (wc >> 6);  // head within q/k/v section

  if (bn < 16) {
    // ---- Q or K block: LN over d=64 + RoPE ----
    const bool isQ = (bn < 8);
    const float* gp = isQ ? qg : kg;
    const float* bp = isQ ? qb : kb;
    float gv[4], bvv[4];
#pragma unroll
    for (int n = 0; n < 4; ++n) {
      gv[n] = gp[n * 16 + l15];
      bvv[n] = bp[n * 16 + l15];
    }
#pragma unroll
    for (int m = 0; m < 4; ++m) {
#pragma unroll
      for (int r = 0; r < 4; ++r) {
        const int tok = bm * 128 + wr + m * 16 + lg * 4 + r;
        const int ntk = tok & 1023, bb = tok >> 10;
        float vals[4];
#pragma unroll
        for (int n = 0; n < 4; ++n) vals[n] = acc[m][n][r] + biasv[n];
        float s = vals[0] + vals[1] + vals[2] + vals[3];
#pragma unroll
        for (int off = 1; off < 16; off <<= 1) s += __shfl_xor(s, off);
        const float mean = s * (1.f / 64.f);
        float cn[4], vs = 0.f;
#pragma unroll
        for (int n = 0; n < 4; ++n) {
          cn[n] = vals[n] - mean;
          vs += cn[n] * cn[n];
        }
#pragma unroll
        for (int off = 1; off < 16; off <<= 1) vs += __shfl_xor(vs, off);
        const float rstd = 1.f / sqrtf(vs * (1.f / 64.f) + 1e-5f);
        float norm[4];
#pragma unroll
        for (int n = 0; n < 4; ++n) norm[n] = cn[n] * rstd * gv[n] + bvv[n];
        const long rb = (long)ntk * 128;
        const long obase = (long)(bb * 16 + h) * 65536 + (long)ntk * 64;
#pragma unroll
        for (int n = 0; n < 4; ++n) {
          const float sinv = rope[rb + n * 16 + l15];
          const float cosv = rope[rb + 64 + n * 16 + l15];
          const float sgn = (n < 2) ? -1.f : 1.f;
          const float outv = norm[n] * cosv + sgn * norm[n ^ 2] * sinv;
          if (isQ) {
            Q[obase + n * 16 + l15] = f2bf(outv);
          } else {
            const int c = n * 2 + (l15 >> 3);
            Ksw[obase + ((c ^ (ntk & 7)) * 8) + (l15 & 7)] = f2bf(outv);
          }
        }
      }
    }
  } else {
    // ---- V block: mix with vres, transpose via LDS, write VTsw ----
    const float l1 = pl1[0], l2 = pl2[0];
    const int hv = (bn - 16) * 2 + (wc >> 6);
    const int myphase = w >> 1, widx = w & 1;
    const int tokbase = bm * 128 + wr;
    const int ntk0 = tokbase & 1023, bbw = tokbase >> 10;
    const long vrb = ((long)(bbw * 16 + hv) * 1024 + ntk0) * 64;
    const long vtb = (long)(bbw * 16 + hv) * 64;
#pragma unroll
    for (int p = 0; p < 2; ++p) {
      if (myphase == p) {
#pragma unroll
        for (int m = 0; m < 4; ++m)
#pragma unroll
          for (int r = 0; r < 4; ++r) {
            const int tl = m * 16 + lg * 4 + r;
#pragma unroll
            for (int n = 0; n < 4; ++n) {
              const int d = n * 16 + l15;
              const float vv = l1 * (acc[m][n][r] + biasv[n]) +
                               l2 * vres[vrb + (long)tl * 64 + d];
              vsc[widx][tl][d] = f2bf(vv);
            }
          }
      }
      __syncthreads();
      if (myphase == p) {
#pragma unroll
        for (int it = 0; it < 8; ++it) {
          const int task = it * 64 + l;
          const int dd = task >> 3, cc = task & 7;
          short8 o;
#pragma unroll
          for (int u = 0; u < 8; ++u) o[u] = (short)vsc[widx][cc * 8 + u][dd];
          *(short8*)&VTsw[(vtb + dd) * 1024 + ntk0 + ((cc ^ (dd & 7)) * 8)] = o;
        }
      }
      __syncthreads();
    }
  }
}

// -------- flash attention fwd v8: in-register P + KVBLK=128 (round-11) --------
__global__ __launch_bounds__(256, 4)
void attn_fwd8(const u16* __restrict__ Q, const u16* __restrict__ Ksw,
               const u16* __restrict__ VTsw, u16* __restrict__ Out) {
  __shared__ u16 Kl[128 * 64];
  __shared__ u16 Vl[64 * 128];
  const int t = threadIdx.x, w = t >> 6, l = t & 63;
  const int l15 = l & 15, lg = l >> 4;
  const int x7 = l15 & 7;
  const int bh = blockIdx.x, q0 = blockIdx.y * 64;
  const long bo = (long)bh * 65536;
  const bool hihalf = (l & 16) != 0;

  const int qrow = q0 + w * 16 + l15;
  short8 qf[2];
#pragma unroll
  for (int ks = 0; ks < 2; ++ks)
    qf[ks] = *(const short8*)&Q[bo + (long)qrow * 64 + ks * 32 + lg * 8];

  f32x4 acc[4] = {};
  float m_run = -1e30f, l_run = 0.f;

  for (int kb = 0; kb < 8; ++kb) {
    const int kvb = kb * 128;
#pragma unroll
    for (int i = 0; i < 4; ++i) {
      const int idx = i * 256 + t;
      const int krow = idx >> 3, kseg = idx & 7;
      gload_lds16(Ksw + bo + (long)(kvb + krow) * 64 + kseg * 8, (char*)Kl + idx * 16);
      const int vd = idx >> 4, vc = idx & 15;
      gload_lds16(VTsw + bo + (long)vd * 1024 + kvb + vc * 8,
                  (char*)Vl + vd * 256 + vc * 16);
    }
    __syncthreads();
#pragma unroll
    for (int tb = 0; tb < 2; ++tb) {
      f32x4 p[4];
#pragma unroll
      for (int mt = 0; mt < 4; ++mt) {
        f32x4 ps = {};
#pragma unroll
        for (int ks = 0; ks < 2; ++ks) {
          const short8 kf = *(const short8*)&Kl[(tb * 64 + mt * 16 + l15) * 64 +
                                                (((ks * 4 + lg) ^ x7) * 8)];
          ps = __builtin_amdgcn_mfma_f32_16x16x32_bf16(kf, qf[ks], ps, 0, 0, 0);
        }
        p[mt] = ps;
      }
      float mx = p[0][0];
#pragma unroll
      for (int mt = 0; mt < 4; ++mt)
#pragma unroll
        for (int r = 0; r < 4; ++r) mx = fmaxf(mx, p[mt][r]);
      mx = fmaxf(mx, __shfl_xor(mx, 16));
      mx = fmaxf(mx, __shfl_xor(mx, 32));
      const float mnew = fmaxf(m_run, mx * 0.125f);
      const float alpha = __expf(m_run - mnew);
      m_run = mnew;
      float sum = 0.f;
#pragma unroll
      for (int mt = 0; mt < 4; ++mt)
#pragma unroll
        for (int r = 0; r < 4; ++r) {
          const float e = __expf(p[mt][r] * 0.125f - mnew);
          p[mt][r] = e;
          sum += e;
        }
      sum += __shfl_xor(sum, 16);
      sum += __shfl_xor(sum, 32);
      l_run = l_run * alpha + sum;
      uint32_t u0[4], u1[4];
#pragma unroll
      for (int mt = 0; mt < 4; ++mt) {
        u0[mt] = cvt_pk_bf16(p[mt][0], p[mt][1]);
        u1[mt] = cvt_pk_bf16(p[mt][2], p[mt][3]);
      }
#pragma unroll
      for (int mt = 0; mt < 4; ++mt)
#pragma unroll
        for (int r = 0; r < 4; ++r) acc[mt][r] *= alpha;
#pragma unroll
      for (int ks = 0; ks < 2; ++ks) {
        uint32_t X0 = u0[2 * ks], Y0 = u0[2 * ks + 1];
        asm("v_permlane32_swap_b32 %0, %1" : "+v"(X0), "+v"(Y0));
        uint32_t X1 = u1[2 * ks], Y1 = u1[2 * ks + 1];
        asm("v_permlane32_swap_b32 %0, %1" : "+v"(X1), "+v"(Y1));
        const uint32_t Xs0 = (uint32_t)__shfl_xor((int)X0, 16);
        const uint32_t Ys0 = (uint32_t)__shfl_xor((int)Y0, 16);
        const uint32_t Xs1 = (uint32_t)__shfl_xor((int)X1, 16);
        const uint32_t Ys1 = (uint32_t)__shfl_xor((int)Y1, 16);
        u32x4 pv;
        pv[0] = hihalf ? Ys0 : X0;
        pv[1] = hihalf ? Ys1 : X1;
        pv[2] = hihalf ? Y0 : Xs0;
        pv[3] = hihalf ? Y1 : Xs1;
        const short8 pf = __builtin_bit_cast(short8, pv);
#pragma unroll
        for (int mt = 0; mt < 4; ++mt) {
          const short8 vf = *(const short8*)&Vl[(mt * 16 + l15) * 128 + tb * 64 +
                                                (((ks * 4 + lg) ^ x7) * 8)];
          acc[mt] = __builtin_amdgcn_mfma_f32_16x16x32_bf16(vf, pf, acc[mt], 0, 0, 0);
        }
      }
    }
    __syncthreads();
  }
  const int b = bh >> 4, h = bh & 15;
  const float inv = 1.f / l_run;
  const long obase = ((long)(b * 1024 + qrow)) * 1024 + h * 64;
#pragma unroll
  for (int mt = 0; mt < 4; ++mt) {
    const long o = obase + mt * 16 + lg * 4;
    *(uint32_t*)&Out[o] = cvt_pk_bf16(acc[mt][0] * inv, acc[mt][1] * inv);
    *(uint32_t*)&Out[o + 2] = cvt_pk_bf16(acc[mt][2] * inv, acc[mt][3] * inv);
  }
}

extern "C" void kernel_launch(void* const* d_in, const int* in_sizes, int n_in,
                              void* d_out, int out_size, void* d_ws, size_t ws_size,
                              hipStream_t stream) {
  const float* x     = (const float*)d_in[0];
  const float* rope  = (const float*)d_in[1];
  const float* dte   = (const float*)d_in[2];
  const float* vres  = (const float*)d_in[3];
  const float* Wqkv  = (const float*)d_in[4];
  const float* bqkv  = (const float*)d_in[5];
  const float* Wdt   = (const float*)d_in[6];
  const float* bdt   = (const float*)d_in[7];
  const float* qn_g  = (const float*)d_in[8];
  const float* qn_b  = (const float*)d_in[9];
  const float* kn_g  = (const float*)d_in[10];
  const float* kn_b  = (const float*)d_in[11];
  const float* l1    = (const float*)d_in[12];
  const float* l2    = (const float*)d_in[13];
  const float* Wproj = (const float*)d_in[14];
  const float* bproj = (const float*)d_in[15];
  float* out = (float*)d_out;

  char* ws = (char*)d_ws;
  u16*   A_cat = (u16*)(ws);                    // [4096,2048] bf16
  u16*   W_cat = (u16*)(ws + 16777216);         // [3072,2048] bf16
  u16*   Wp    = (u16*)(ws + 29360128);         // [1024,1024] bf16
  u16*   Qb    = (u16*)(ws + 56623104);         // [64,1024,64] bf16
  u16*   Ksw   = (u16*)(ws + 65011712);         // swizzled K
  u16*   VTsw  = (u16*)(ws + 73400320);         // swizzled V^T
  u16*   AO    = (u16*)(ws + 81788928);         // [4096,1024] bf16
  // total ws usage: 90,177,536 bytes

  cvt_all<<<2048, 256, 0, stream>>>(x, dte, Wqkv, Wdt, Wproj, A_cat, W_cat, Wp);
  // fused QKV GEMM + LN/RoPE/v-mix epilogue -> Q, Ksw, VTsw directly
  gemm_qkv_fused<<<dim3(32, 24), 256, 0, stream>>>(
      A_cat, W_cat, bqkv, bdt, vres, rope, qn_g, qn_b, kn_g, kn_b, l1, l2,
      Qb, Ksw, VTsw, 4096, 3072, 2048);
  attn_fwd8<<<dim3(64, 16), 256, 0, stream>>>(Qb, Ksw, VTsw, AO);
  gemm_bt64<<<dim3(64, 8), 256, 0, stream>>>(AO, Wp, out, bproj, 4096, 1024, 1024);
}